// Round 14
// baseline (414.583 us; speedup 1.0000x reference)
//
#include <hip/hip_runtime.h>
#include <hip/hip_bf16.h>
#include <math.h>

constexpr int IN_DIM  = 768;
constexpr int HID     = 128;
constexpr int OUT_DIM = 256;
constexpr int SEM     = 512;     // HID*HEADS
constexpr int N_USER  = 50000;
constexpr int N_LLM   = 5000;
constexpr int NE      = 400000;

constexpr int MP_USER = 50048;   // 391*128
constexpr int MP_LLM  = 5120;    // 40*128
constexpr int MP_2U   = 100096;  // 782*128
constexpr int GY_USER = MP_USER / 128;   // 391
constexpr int GY_LLM  = MP_LLM / 128;    // 40

typedef unsigned int uint;
typedef unsigned short ushort;
typedef __attribute__((ext_vector_type(8))) short bf16x8;
typedef __attribute__((ext_vector_type(4))) float f32x4;

constexpr int cdiv(int a, int b) { return (a + b - 1) / b; }

__device__ __forceinline__ ushort f2b(float f) {
  uint u = __float_as_uint(f);
  u += 0x7FFFu + ((u >> 16) & 1u);       // RNE
  return (ushort)(u >> 16);
}
__device__ __forceinline__ float b2f(uint bits16) {
  return __uint_as_float(bits16 << 16);
}

__device__ __forceinline__ float fexp2(float x) { return __builtin_amdgcn_exp2f(x); }
#define LOG2E 1.4426950408889634f

#define GLOAD_LDS16(g, l) __builtin_amdgcn_global_load_lds( \
    (const __attribute__((address_space(1))) void*)(g), \
    (__attribute__((address_space(3))) void*)(l), 16, 0, 0)

// LDS XOR swizzle (T2, rule #21): linear LDS dest (gload_lds), pre-permuted
// GLOBAL source slot; reads XOR slot with (row&7). 16-way conflict -> 2-way.

// Z layout: interleaved — row (2*node + path). Consumers (T-GEMM, beta,
// gemm_out) use the same mapping; adjacent paths give DRAM locality.

// ---------------- generic bf16 MFMA GEMM (bf16 store) ----------------------
__global__ __launch_bounds__(256) void gemm_bf16_0(
    const ushort* __restrict__ A, const ushort* __restrict__ Bt,
    ushort* __restrict__ Cout, int N, int K)
{
  __shared__ ushort As[128][64];
  __shared__ ushort Bs[128][64];
  const int t = threadIdx.x;
  const int wid = t >> 6, lane = t & 63;

  const int nwg  = gridDim.x * gridDim.y;
  const int orig = blockIdx.y * gridDim.x + blockIdx.x;
  const int q = nwg >> 3, r = nwg & 7;
  const int xcd = orig & 7, idx = orig >> 3;
  const int swz = (xcd < r ? xcd * (q + 1) : r * (q + 1) + (xcd - r) * q) + idx;
  const int bxi = swz % gridDim.x, byi = swz / gridDim.x;

  const int bm = byi * 128, bn = bxi * 128;
  const int lr = lane & 15, kg = lane >> 4;
  const int sw8 = lr & 7;
  const int mbase = (wid >> 1) * 64, nbase = (wid & 1) * 64;
  const int grow = lane >> 3;                         // 0..7
  const int gcol = (((lane & 7) ^ grow)) * 8;         // pre-swizzled source slot

  f32x4 acc[4][4] = {};

  for (int k0 = 0; k0 < K; k0 += 64) {
#pragma unroll
    for (int c = 0; c < 4; ++c) {
      int ch = wid * 4 + c;
      GLOAD_LDS16(A  + (size_t)(bm + ch * 8 + grow) * K + k0 + gcol, &As[ch * 8][0]);
      GLOAD_LDS16(Bt + (size_t)(bn + ch * 8 + grow) * K + k0 + gcol, &Bs[ch * 8][0]);
    }
    asm volatile("s_waitcnt vmcnt(0)" ::: "memory");
    __syncthreads();
#pragma unroll
    for (int kb = 0; kb < 2; ++kb) {
      const int csw = ((kb * 4 + kg) ^ sw8) * 8;      // swizzled read slot
      bf16x8 av[4], bv[4];
#pragma unroll
      for (int m = 0; m < 4; ++m)
        av[m] = *(const bf16x8*)&As[mbase + m * 16 + lr][csw];
#pragma unroll
      for (int n = 0; n < 4; ++n)
        bv[n] = *(const bf16x8*)&Bs[nbase + n * 16 + lr][csw];
#pragma unroll
      for (int m = 0; m < 4; ++m)
#pragma unroll
        for (int n = 0; n < 4; ++n)
          acc[m][n] = __builtin_amdgcn_mfma_f32_16x16x32_bf16(av[m], bv[n], acc[m][n], 0, 0, 0);
    }
    __syncthreads();
  }

#pragma unroll
  for (int m = 0; m < 4; ++m)
#pragma unroll
    for (int j = 0; j < 4; ++j) {
      int row = bm + mbase + m * 16 + kg * 4 + j;
#pragma unroll
      for (int n = 0; n < 4; ++n) {
        int col = bn + nbase + n * 16 + lr;
        Cout[(size_t)row * N + col] = f2b(acc[m][n][j]);
      }
    }
}

// ------------- merged hs GEMM (user + llm), 3 col-tiles --------------------
// Grid (3, GY_USER+GY_LLM). Col tiles: {0:cols 0-255, 1:cols 256-511} -> bf16
// hs (acc[4][8]); {2: B rows 512-639, logit fp32 (acc[4][4], cols 0-15)}.
// A staged once per (M-tile, col-tile) => 3x A re-read (was 5x).
__global__ __launch_bounds__(256) void gemm_hs(
    const ushort* __restrict__ A_u, const ushort* __restrict__ A_l,
    const ushort* __restrict__ Bt_u, const ushort* __restrict__ Bt_l,
    ushort* __restrict__ hs_u, ushort* __restrict__ hs_l,
    float* __restrict__ logU, float* __restrict__ logL)
{
  __shared__ ushort As[128][64];   // 16 KB
  __shared__ ushort Bs[256][64];   // 32 KB
  const int t = threadIdx.x;
  const int wid = t >> 6, lane = t & 63;
  const int K = IN_DIM;

  const int nwg  = gridDim.x * gridDim.y;
  const int orig = blockIdx.y * gridDim.x + blockIdx.x;
  const int q = nwg >> 3, r = nwg & 7;
  const int xcd = orig & 7, idx = orig >> 3;
  const int swz = (xcd < r ? xcd * (q + 1) : r * (q + 1) + (xcd - r) * q) + idx;
  const int bxi = swz % gridDim.x, byi0 = swz / gridDim.x;

  const bool llm = (byi0 >= GY_USER);
  const int byi = llm ? byi0 - GY_USER : byi0;
  const ushort* A    = llm ? A_l : A_u;
  const ushort* Bt   = llm ? Bt_l : Bt_u;
  ushort* hs         = llm ? hs_l : hs_u;
  float* logit       = llm ? logL : logU;

  const bool logt = (bxi == 2);
  const int bm = byi * 128;
  const int bnrow = logt ? 512 : bxi * 256;   // B row offset
  const int lr = lane & 15, kg = lane >> 4;
  const int sw8 = lr & 7;
  const int mbase = (wid >> 1) * 64;
  const int nbase = (wid & 1) * (logt ? 64 : 128);
  const int grow = lane >> 3;
  const int gcol = (((lane & 7) ^ grow)) * 8;

  f32x4 acc[4][8] = {};

  for (int k0 = 0; k0 < K; k0 += 64) {
#pragma unroll
    for (int c = 0; c < 4; ++c) {
      int ch = wid * 4 + c;
      GLOAD_LDS16(A + (size_t)(bm + ch * 8 + grow) * K + k0 + gcol, &As[ch * 8][0]);
    }
    if (logt) {
#pragma unroll
      for (int c = 0; c < 4; ++c) {
        int ch = wid * 4 + c;            // 0..15 -> 128 B rows
        GLOAD_LDS16(Bt + (size_t)(bnrow + ch * 8 + grow) * K + k0 + gcol, &Bs[ch * 8][0]);
      }
    } else {
#pragma unroll
      for (int c = 0; c < 8; ++c) {
        int ch = wid * 8 + c;            // 0..31 -> 256 B rows
        GLOAD_LDS16(Bt + (size_t)(bnrow + ch * 8 + grow) * K + k0 + gcol, &Bs[ch * 8][0]);
      }
    }
    asm volatile("s_waitcnt vmcnt(0)" ::: "memory");
    __syncthreads();
#pragma unroll
    for (int kb = 0; kb < 2; ++kb) {
      const int csw = ((kb * 4 + kg) ^ sw8) * 8;
      bf16x8 av[4], bv[8];
#pragma unroll
      for (int m = 0; m < 4; ++m)
        av[m] = *(const bf16x8*)&As[mbase + m * 16 + lr][csw];
      if (logt) {
#pragma unroll
        for (int n = 0; n < 4; ++n)
          bv[n] = *(const bf16x8*)&Bs[nbase + n * 16 + lr][csw];
#pragma unroll
        for (int m = 0; m < 4; ++m)
#pragma unroll
          for (int n = 0; n < 4; ++n)
            acc[m][n] = __builtin_amdgcn_mfma_f32_16x16x32_bf16(av[m], bv[n], acc[m][n], 0, 0, 0);
      } else {
#pragma unroll
        for (int n = 0; n < 8; ++n)
          bv[n] = *(const bf16x8*)&Bs[nbase + n * 16 + lr][csw];
#pragma unroll
        for (int m = 0; m < 4; ++m)
#pragma unroll
          for (int n = 0; n < 8; ++n)
            acc[m][n] = __builtin_amdgcn_mfma_f32_16x16x32_bf16(av[m], bv[n], acc[m][n], 0, 0, 0);
      }
    }
    __syncthreads();
  }

  if (logt) {
    if (nbase == 0) {
#pragma unroll
      for (int m = 0; m < 4; ++m)
#pragma unroll
        for (int j = 0; j < 4; ++j) {
          int row = bm + mbase + m * 16 + kg * 4 + j;
          logit[(size_t)row * 16 + lr] = acc[m][0][j];
        }
    }
    return;
  }

#pragma unroll
  for (int m = 0; m < 4; ++m)
#pragma unroll
    for (int j = 0; j < 4; ++j) {
      int row = bm + mbase + m * 16 + kg * 4 + j;
#pragma unroll
      for (int n = 0; n < 8; ++n) {
        int col = bxi * 256 + nbase + n * 16 + lr;
        hs[(size_t)row * SEM + col] = f2b(acc[m][n][j]);
      }
    }
}

// ------------- fused combine + out GEMM: 128x256 tile, single N pass -------
// A synthesized as beta.x*Z[2*row] + beta.y*Z[2*row+1] (interleaved layout).
__global__ __launch_bounds__(256) void gemm_out(
    const ushort* __restrict__ Z, const ushort* __restrict__ WtO,
    float* __restrict__ out, const float* __restrict__ out_b,
    const float2* __restrict__ beta)
{
  __shared__ ushort As[128][64];   // 16 KB
  __shared__ ushort Bs[256][64];   // 32 KB
  const int t = threadIdx.x;
  const int wid = t >> 6, lane = t & 63;
  const int K = SEM;

  const int nwg  = gridDim.x;
  const int orig = blockIdx.x;
  const int q = nwg >> 3, r = nwg & 7;
  const int xcd = orig & 7, idx = orig >> 3;
  const int swz = (xcd < r ? xcd * (q + 1) : r * (q + 1) + (xcd - r) * q) + idx;

  const int bm = swz * 128;
  const int lr = lane & 15, kg = lane >> 4;
  const int sw8 = lr & 7;
  const int mbase = (wid >> 1) * 64, nbase = (wid & 1) * 128;
  const int grow = lane >> 3;
  const int gcol = (((lane & 7) ^ grow)) * 8;
  const int wcol = (((lane & 7) ^ grow)) * 8;   // swizzled ds_write slot

  f32x4 acc[4][8] = {};

  for (int k0 = 0; k0 < K; k0 += 64) {
#pragma unroll
    for (int c = 0; c < 8; ++c) {
      int ch = wid * 8 + c;            // 0..31
      GLOAD_LDS16(WtO + (size_t)(ch * 8 + grow) * K + k0 + gcol, &Bs[ch * 8][0]);
    }
#pragma unroll
    for (int c = 0; c < 4; ++c) {
      int ch = wid * 4 + c;
      int rl = ch * 8 + grow;          // 0..127 ; rl&7 == grow
      int row = bm + rl;
      const ushort* z0p = Z + (size_t)(2 * row) * SEM + k0 + (lane & 7) * 8;
      const ushort* z1p = z0p + SEM;
      float2 bb = beta[row];
      uint4 a0 = *(const uint4*)z0p;
      uint4 a1 = *(const uint4*)z1p;
      uint rpk[4];
#pragma unroll
      for (int qq = 0; qq < 4; ++qq) {
        uint x0 = ((const uint*)&a0)[qq], x1 = ((const uint*)&a1)[qq];
        float lo = bb.x * b2f(x0 & 0xffffu) + bb.y * b2f(x1 & 0xffffu);
        float hi = bb.x * b2f(x0 >> 16)     + bb.y * b2f(x1 >> 16);
        rpk[qq] = (uint)f2b(lo) | ((uint)f2b(hi) << 16);
      }
      *(uint4*)&As[rl][wcol] = make_uint4(rpk[0], rpk[1], rpk[2], rpk[3]);
    }
    asm volatile("s_waitcnt vmcnt(0)" ::: "memory");
    __syncthreads();
#pragma unroll
    for (int kb = 0; kb < 2; ++kb) {
      const int csw = ((kb * 4 + kg) ^ sw8) * 8;
      bf16x8 av[4], bv[8];
#pragma unroll
      for (int m = 0; m < 4; ++m)
        av[m] = *(const bf16x8*)&As[mbase + m * 16 + lr][csw];
#pragma unroll
      for (int n = 0; n < 8; ++n)
        bv[n] = *(const bf16x8*)&Bs[nbase + n * 16 + lr][csw];
#pragma unroll
      for (int m = 0; m < 4; ++m)
#pragma unroll
        for (int n = 0; n < 8; ++n)
          acc[m][n] = __builtin_amdgcn_mfma_f32_16x16x32_bf16(av[m], bv[n], acc[m][n], 0, 0, 0);
    }
    __syncthreads();
  }

#pragma unroll
  for (int m = 0; m < 4; ++m)
#pragma unroll
    for (int j = 0; j < 4; ++j) {
      int row = bm + mbase + m * 16 + kg * 4 + j;
      if (row >= N_USER) continue;
#pragma unroll
      for (int n = 0; n < 8; ++n) {
        int col = nbase + n * 16 + lr;
        out[(size_t)row * OUT_DIM + col] = acc[m][n][j] + out_b[col];
      }
    }
}

// ---------------- mega prep kernel (grid-strided) --------------------------
constexpr int NB_FOLD  = cdiv(IN_DIM * 16, 256);            // 48
constexpr int NB_CASTU = N_USER * IN_DIM / 8 / 256;         // 18750
constexpr int NB_CASTL = N_LLM * IN_DIM / 8 / 256;          // 1875
constexpr int NB_TTW   = (IN_DIM / 64) * (SEM / 64);        // 96 (x2)
constexpr int NB_TTS   = (SEM / 64) * (HID / 64);           // 16
constexpr int NB_TTO   = (SEM / 64) * (OUT_DIM / 64);       // 32
constexpr int NB_E1    = cdiv(2 * NE, 256);                 // 3125
constexpr int PB0 = NB_FOLD;
constexpr int PB1 = PB0 + NB_CASTU;
constexpr int PB2 = PB1 + NB_CASTL;
constexpr int PB3 = PB2 + NB_TTW;
constexpr int PB4 = PB3 + NB_TTW;
constexpr int PB5 = PB4 + NB_TTS;
constexpr int PB6 = PB5 + NB_TTO;
constexpr int PB7 = PB6 + NB_E1;
constexpr int PREP_GRID = 2048;

// LDS-tiled transpose-cast: W fp32 [K][Nw] -> Bt bf16 [Nw][K], 64x64 tile.
__device__ __forceinline__ void tt_body(const float* __restrict__ W,
                                        ushort* __restrict__ Bt,
                                        int K, int Nw, int tile,
                                        float (*lds)[65], int t)
{
  const int tiles_n = Nw >> 6;
  const int tk = tile / tiles_n, tn = tile - tk * tiles_n;
  const int k0 = tk << 6, n0 = tn << 6;
#pragma unroll
  for (int i = 0; i < 16; ++i) {
    int idx = t + i * 256;
    int rr = idx >> 6, cc = idx & 63;
    lds[rr][cc] = W[(size_t)(k0 + rr) * Nw + n0 + cc];
  }
  __syncthreads();
#pragma unroll
  for (int i = 0; i < 4; ++i) {
    int idx = t + i * 256;                 // 0..1023
    int cc = idx >> 4;                     // 0..63 (output row = n0+cc)
    int rq = (idx & 15) * 4;               // 0,4,...,60
    uint lo = (uint)f2b(lds[rq][cc])     | ((uint)f2b(lds[rq + 1][cc]) << 16);
    uint hi = (uint)f2b(lds[rq + 2][cc]) | ((uint)f2b(lds[rq + 3][cc]) << 16);
    *(uint2*)(Bt + (size_t)(n0 + cc) * K + k0 + rq) = make_uint2(lo, hi);
  }
  __syncthreads();
}

__device__ __forceinline__ void cast_body(const float* __restrict__ x,
                                          ushort* __restrict__ xb, int i)
{
  const float4 a = *(const float4*)(x + (size_t)i * 8);
  const float4 c = *(const float4*)(x + (size_t)i * 8 + 4);
  uint4 o;
  o.x = (uint)f2b(a.x) | ((uint)f2b(a.y) << 16);
  o.y = (uint)f2b(a.z) | ((uint)f2b(a.w) << 16);
  o.z = (uint)f2b(c.x) | ((uint)f2b(c.y) << 16);
  o.w = (uint)f2b(c.z) | ((uint)f2b(c.w) << 16);
  *(uint4*)(xb + (size_t)i * 8) = o;
}

__global__ __launch_bounds__(256) void prep_kernel(
    const float* __restrict__ x_user, const float* __restrict__ x_llm,
    ushort* __restrict__ xb_u, ushort* __restrict__ xb_l,
    const float* __restrict__ Wdst0, const float* __restrict__ adst0,
    const float* __restrict__ Wdst1, const float* __restrict__ adst1,
    const float* __restrict__ Wsrc1, const float* __restrict__ asrc1,
    const float* __restrict__ Wsrc0, const float* __restrict__ asrc0,
    ushort* __restrict__ Wt1x, ushort* __restrict__ Wt0x,
    const float* __restrict__ sem_W1, ushort* __restrict__ WtS,
    const float* __restrict__ out_W, ushort* __restrict__ WtO,
    const int* __restrict__ dst0, const int* __restrict__ dst1,
    int* __restrict__ deg, int* __restrict__ rank)
{
  __shared__ float lds[64][65];   // 16.6 KB, used by transpose sections
  const int t = threadIdx.x;
  for (int b = blockIdx.x; b < PB7; b += PREP_GRID) {
    if (b < PB0) {
      int idxg = b * 256 + t;
      if (idxg < IN_DIM * 16) {
        int k = idxg >> 4, hh = idxg & 15;
        const float* W;
        const float* att;
        if (hh < 4)       { W = Wdst0; att = adst0; }
        else if (hh < 8)  { W = Wdst1; att = adst1; }
        else if (hh < 12) { W = Wsrc1; att = asrc1; }
        else              { W = Wsrc0; att = asrc0; }
        int h = hh & 3;
        float s = 0.f;
#pragma unroll 4
        for (int c = 0; c < HID; ++c)
          s += W[(size_t)k * SEM + h * HID + c] * att[h * HID + c];
        if (hh < 12) Wt1x[(size_t)(512 + hh) * IN_DIM + k] = f2b(s);
        else         Wt0x[(size_t)(512 + h) * IN_DIM + k] = f2b(s);
      }
    } else if (b < PB1) {
      cast_body(x_user, xb_u, (b - PB0) * 256 + t);
    } else if (b < PB2) {
      cast_body(x_llm, xb_l, (b - PB1) * 256 + t);
    } else if (b < PB3) {
      tt_body(Wsrc0, Wt0x, IN_DIM, SEM, b - PB2, lds, t);
    } else if (b < PB4) {
      tt_body(Wsrc1, Wt1x, IN_DIM, SEM, b - PB3, lds, t);
    } else if (b < PB5) {
      tt_body(sem_W1, WtS, SEM, HID, b - PB4, lds, t);
    } else if (b < PB6) {
      tt_body(out_W, WtO, SEM, OUT_DIM, b - PB5, lds, t);
    } else {
      int e = (b - PB6) * 256 + t;
      if (e < 2 * NE) {
        int d = (e < NE) ? dst0[e] : (dst1[e - NE] + N_USER);
        rank[e] = atomicAdd(&deg[d], 1);
      }
    }
  }
}

// -------- scatter src (ushort) into CSR slots — atomic-free, grid-strided --
__global__ void scatter_kernel(const int* __restrict__ src0, const int* __restrict__ dst0,
                               const int* __restrict__ src1, const int* __restrict__ dst1,
                               const int* __restrict__ rp, const int* __restrict__ rank,
                               ushort* __restrict__ scsr)
{
  for (int e = blockIdx.x * 256 + threadIdx.x; e < 2 * NE; e += gridDim.x * 256) {
    bool p1 = (e >= NE);
    int ee = p1 ? e - NE : e;
    int s = p1 ? src1[ee] : src0[ee];
    int d = p1 ? (dst1[ee] + N_USER) : dst0[ee];
    scsr[rp[d] + rank[e]] = (ushort)s;
  }
}

// -------- 3-phase scan over deg[0..n) --------------------------------------
__global__ __launch_bounds__(256) void scan1(const int* __restrict__ deg,
                                             int* __restrict__ bsum, int n)
{
  __shared__ int sm[256];
  int b = blockIdx.x, t = threadIdx.x;
  int base = b * 1024 + t * 4;
  int s = 0;
#pragma unroll
  for (int i = 0; i < 4; ++i) if (base + i < n) s += deg[base + i];
  sm[t] = s;
  __syncthreads();
  for (int off = 128; off > 0; off >>= 1) {
    if (t < off) sm[t] += sm[t + off];
    __syncthreads();
  }
  if (t == 0) bsum[b] = sm[0];
}

__global__ __launch_bounds__(128) void scan2(const int* __restrict__ bsum,
                                             int* __restrict__ boff, int nb,
                                             int* __restrict__ rp_tail, int tailval)
{
  __shared__ int sm[128];
  int t = threadIdx.x;
  int v = (t < nb) ? bsum[t] : 0;
  sm[t] = v;
  __syncthreads();
  for (int off = 1; off < 128; off <<= 1) {
    int x = (t >= off) ? sm[t - off] : 0;
    __syncthreads();
    sm[t] += x;
    __syncthreads();
  }
  if (t < nb) boff[t] = sm[t] - v;
  if (t == 0) *rp_tail = tailval;
}

__global__ __launch_bounds__(256) void scan3(const int* __restrict__ deg,
                                             const int* __restrict__ boff,
                                             int* __restrict__ rp, int n)
{
  __shared__ int sm[256];
  int b = blockIdx.x, t = threadIdx.x;
  int base = b * 1024 + t * 4;
  int v[4];
#pragma unroll
  for (int i = 0; i < 4; ++i) v[i] = (base + i < n) ? deg[base + i] : 0;
  int tsum = v[0] + v[1] + v[2] + v[3];
  sm[t] = tsum;
  __syncthreads();
  for (int off = 1; off < 256; off <<= 1) {
    int x = (t >= off) ? sm[t - off] : 0;
    __syncthreads();
    sm[t] += x;
    __syncthreads();
  }
  int run = sm[t] - tsum + boff[b];
#pragma unroll
  for (int i = 0; i < 4; ++i) {
    if (base + i < n) rp[base + i] = run;
    run += v[i];
  }
}

// -------- unified aggregation: ONE WAVE per dst node -----------------------
// Writes Z in interleaved layout: row = 2*nd + path.
__global__ __launch_bounds__(64) void agg_kernel(
    const ushort* __restrict__ hs0, const ushort* __restrict__ hs1,
    const ushort* __restrict__ srcs,
    const float* __restrict__ logitL, const float* __restrict__ logitU,
    const int* __restrict__ rp,
    const float* __restrict__ bias0, const float* __restrict__ bias1,
    ushort* __restrict__ Zout)
{
  __shared__ ushort s_src[64];
  __shared__ float  s_ev[64][4];
  int node = blockIdx.x, lane = threadIdx.x;
  bool p1 = (node >= N_USER);
  const ushort* hs   = p1 ? hs1 : hs0;
  const float*  bias = p1 ? bias1 : bias0;
  int nd = p1 ? node - N_USER : node;
  float4 ad4 = *(const float4*)(logitU + (size_t)nd * 16 + (p1 ? 4 : 0));
  ad4.x *= LOG2E; ad4.y *= LOG2E; ad4.z *= LOG2E; ad4.w *= LOG2E;
  const float* asbase = p1 ? (logitU + 8) : logitL;
  int h  = lane >> 4;
  int cb = lane * 8;
  float acc[8] = {};
  float dsum = 0.f;
  int jb = rp[node], je = rp[node + 1];
  for (int j0 = jb; j0 < je; j0 += 64) {
    int n = min(64, je - j0);
    __syncthreads();
    if (lane < n) {
      int s = srcs[j0 + lane];
      s_src[lane] = (ushort)s;
      float4 as4 = *(const float4*)(asbase + (size_t)s * 16);
      float v0 = as4.x * LOG2E + ad4.x, v1 = as4.y * LOG2E + ad4.y;
      float v2 = as4.z * LOG2E + ad4.z, v3 = as4.w * LOG2E + ad4.w;
      v0 = (v0 > 0.f) ? v0 : 0.2f * v0;
      v1 = (v1 > 0.f) ? v1 : 0.2f * v1;
      v2 = (v2 > 0.f) ? v2 : 0.2f * v2;
      v3 = (v3 > 0.f) ? v3 : 0.2f * v3;
      s_ev[lane][0] = fexp2(v0);
      s_ev[lane][1] = fexp2(v1);
      s_ev[lane][2] = fexp2(v2);
      s_ev[lane][3] = fexp2(v3);
    }
    __syncthreads();
#pragma unroll 4
    for (int j = 0; j < n; ++j) {
      int s = __builtin_amdgcn_readfirstlane((int)s_src[j]);
      float e = s_ev[j][h];
      const uint4 pv = *(const uint4*)(hs + ((size_t)s << 9) + cb);
      acc[0] += b2f(pv.x & 0xffffu) * e;  acc[1] += b2f(pv.x >> 16) * e;
      acc[2] += b2f(pv.y & 0xffffu) * e;  acc[3] += b2f(pv.y >> 16) * e;
      acc[4] += b2f(pv.z & 0xffffu) * e;  acc[5] += b2f(pv.z >> 16) * e;
      acc[6] += b2f(pv.w & 0xffffu) * e;  acc[7] += b2f(pv.w >> 16) * e;
      dsum += e;
    }
  }
  float inv = 1.f / (dsum + 1e-16f);
  float4 b4a = *(const float4*)(bias + cb);
  float4 b4b = *(const float4*)(bias + cb + 4);
  float bb[8] = { b4a.x, b4a.y, b4a.z, b4a.w, b4b.x, b4b.y, b4b.z, b4b.w };
  uint4 o;
  uint* op = (uint*)&o;
#pragma unroll
  for (int i = 0; i < 4; ++i) {
    float z0 = acc[2 * i]     * inv + bb[2 * i];
    float z1 = acc[2 * i + 1] * inv + bb[2 * i + 1];
    z0 = (z0 > 0.f) ? z0 : fexp2(z0 * LOG2E) - 1.f;
    z1 = (z1 > 0.f) ? z1 : fexp2(z1 * LOG2E) - 1.f;
    op[i] = (uint)f2b(z0) | ((uint)f2b(z1) << 16);
  }
  int zrow = 2 * nd + (p1 ? 1 : 0);
  *(uint4*)(Zout + (size_t)zrow * SEM + cb) = o;
}

// -------- beta: semantic softmax weights per node (wave per node) ----------
// T rows interleaved: node's two paths at rows 2*node, 2*node+1.
__global__ __launch_bounds__(256) void beta_kernel(
    const ushort* __restrict__ T, const float* __restrict__ b1,
    const float* __restrict__ W2, float2* __restrict__ beta, int n)
{
  int wid = threadIdx.x >> 6, lane = threadIdx.x & 63;
  int node = blockIdx.x * 4 + wid;
  if (node >= n) return;
  const ushort* t0 = T + (size_t)(2 * node) * HID;
  const ushort* t1 = t0 + HID;
  int j = 2 * lane;
  uint u0 = *(const uint*)(t0 + j);
  uint u1 = *(const uint*)(t1 + j);
  float wa = W2[j], wb = W2[j + 1];
  float ba = b1[j], bb = b1[j + 1];
  auto ftanh = [](float x) {
    x = fminf(fmaxf(x, -20.f), 20.f);
    float e = fexp2(2.f * LOG2E * x);
    return (e - 1.f) / (e + 1.f);
  };
  float s0 = ftanh(b2f(u0 & 0xffffu) + ba) * wa + ftanh(b2f(u0 >> 16) + bb) * wb;
  float s1 = ftanh(b2f(u1 & 0xffffu) + ba) * wa + ftanh(b2f(u1 >> 16) + bb) * wb;
#pragma unroll
  for (int off = 32; off > 0; off >>= 1) {
    s0 += __shfl_down(s0, off);
    s1 += __shfl_down(s1, off);
  }
  if (lane == 0) {
    float mx = fmaxf(s0, s1);
    float e0 = fexp2((s0 - mx) * LOG2E), e1 = fexp2((s1 - mx) * LOG2E);
    float s = e0 + e1;
    beta[node] = make_float2(e0 / s, e1 / s);
  }
}

extern "C" void kernel_launch(void* const* d_in, const int* in_sizes, int n_in,
                              void* d_out, int out_size, void* d_ws, size_t ws_size,
                              hipStream_t stream)
{
  const float* x_user = (const float*)d_in[0];
  const float* x_llm  = (const float*)d_in[1];
  const int* src0 = (const int*)d_in[2];
  const int* dst0 = (const int*)d_in[3];
  const int* src1 = (const int*)d_in[4];
  const int* dst1 = (const int*)d_in[5];
  const float* Wsrc0 = (const float*)d_in[6];
  const float* Wdst0 = (const float*)d_in[7];
  const float* asrc0 = (const float*)d_in[8];
  const float* adst0 = (const float*)d_in[9];
  const float* bias0 = (const float*)d_in[10];
  const float* Wsrc1 = (const float*)d_in[11];
  const float* Wdst1 = (const float*)d_in[12];
  const float* asrc1 = (const float*)d_in[13];
  const float* adst1 = (const float*)d_in[14];
  const float* bias1 = (const float*)d_in[15];
  const float* sem_W1 = (const float*)d_in[16];
  const float* sem_b1 = (const float*)d_in[17];
  const float* sem_W2 = (const float*)d_in[18];
  const float* out_W  = (const float*)d_in[19];
  const float* out_b  = (const float*)d_in[20];

  char* ws = (char*)d_ws;
  size_t off = 0;
  auto alloc = [&](size_t bytes) -> size_t {
    size_t o = off;
    off += (bytes + 255) & ~(size_t)255;
    return o;
  };

  size_t xbu_off  = alloc((size_t)MP_USER * IN_DIM * 2);   // later overlaid by T bf16
  size_t xbl_off  = alloc((size_t)MP_LLM  * IN_DIM * 2);
  size_t wt0_off  = alloc((size_t)640 * IN_DIM * 2);
  size_t wt1_off  = alloc((size_t)640 * IN_DIM * 2);
  size_t wts_off  = alloc((size_t)HID * SEM * 2);
  size_t wto_off  = alloc((size_t)OUT_DIM * SEM * 2);
  size_t hs0_off  = alloc((size_t)MP_LLM  * SEM * 2);
  size_t hs1_off  = alloc((size_t)MP_USER * SEM * 2);
  size_t Z_off    = alloc((size_t)MP_2U   * SEM * 2);
  size_t sc_off   = alloc((size_t)2 * NE * 2);
  size_t rank_off = alloc((size_t)2 * NE * 4);
  size_t lgu_off  = alloc((size_t)MP_USER * 16 * 4);
  size_t lgl_off  = alloc((size_t)MP_LLM  * 16 * 4);
  size_t beta_off = alloc((size_t)MP_USER * 8);
  size_t deg_off  = alloc((size_t)2 * N_USER * 4);         // zeroed
  size_t zero_end = off;
  size_t rp_off   = alloc((size_t)(2 * N_USER + 1) * 4);
  size_t bs_off   = alloc((size_t)128 * 4);
  size_t bo_off   = alloc((size_t)128 * 4);

  ushort* xb_u  = (ushort*)(ws + xbu_off);
  ushort* xb_l  = (ushort*)(ws + xbl_off);
  ushort* Wt0x  = (ushort*)(ws + wt0_off);
  ushort* Wt1x  = (ushort*)(ws + wt1_off);
  ushort* WtS   = (ushort*)(ws + wts_off);
  ushort* WtO   = (ushort*)(ws + wto_off);
  ushort* hs0b  = (ushort*)(ws + hs0_off);
  ushort* hs1b  = (ushort*)(ws + hs1_off);
  ushort* Zsw   = (ushort*)(ws + Z_off);
  ushort* Tbuf  = (ushort*)(ws + xbu_off);  // overlay: xb dead after hs GEMMs
  ushort* scsr  = (ushort*)(ws + sc_off);
  int*    rank  = (int*)(ws + rank_off);
  float*  logU  = (float*)(ws + lgu_off);
  float*  logL  = (float*)(ws + lgl_off);
  float2* beta  = (float2*)(ws + beta_off);
  int*    deg   = (int*)(ws + deg_off);
  int*    rp    = (int*)(ws + rp_off);
  int*    bsum  = (int*)(ws + bs_off);
  int*    boff  = (int*)(ws + bo_off);

  hipMemsetAsync(ws + deg_off, 0, zero_end - deg_off, stream);
  hipMemsetAsync(Wt0x + (size_t)512 * IN_DIM, 0, (size_t)128 * IN_DIM * 2, stream);
  hipMemsetAsync(Wt1x + (size_t)512 * IN_DIM, 0, (size_t)128 * IN_DIM * 2, stream);

  // mega prep (grid-strided): fold + casts + tiled transposes + degree/rank
  prep_kernel<<<PREP_GRID, 256, 0, stream>>>(
      x_user, x_llm, xb_u, xb_l,
      Wdst0, adst0, Wdst1, adst1, Wsrc1, asrc1, Wsrc0, asrc0,
      Wt1x, Wt0x, sem_W1, WtS, out_W, WtO,
      dst0, dst1, deg, rank);

  // CSR build over unified node space
  const int NTOT = 2 * N_USER;
  const int NB = cdiv(NTOT, 1024);   // 98
  scan1<<<NB, 256, 0, stream>>>(deg, bsum, NTOT);
  scan2<<<1, 128, 0, stream>>>(bsum, boff, NB, rp + NTOT, 2 * NE);
  scan3<<<NB, 256, 0, stream>>>(deg, boff, rp, NTOT);
  scatter_kernel<<<2048, 256, 0, stream>>>(src0, dst0, src1, dst1, rp, rank, scsr);

  // merged hs GEMMs (3 col-tiles: 2x256 hs + 1 logit)
  {
    dim3 g(3, GY_USER + GY_LLM);
    gemm_hs<<<g, 256, 0, stream>>>(xb_u, xb_l, Wt1x, Wt0x, hs1b, hs0b, logU, logL);
  }

  // unified aggregation (one wave per node) -> bf16 Z (interleaved rows)
  agg_kernel<<<NTOT, 64, 0, stream>>>(hs0b, hs1b, scsr, logL, logU, rp,
                                      bias0, bias1, Zsw);

  // T = Z @ sem_W1 (bf16 out, overlays dead xb_u; rows interleaved like Z)
  {
    dim3 g(HID / 128, MP_2U / 128);
    gemm_bf16_0<<<g, 256, 0, stream>>>(Zsw, WtS, Tbuf, HID, SEM);
  }

  // semantic softmax weights (interleaved T rows)
  beta_kernel<<<cdiv(N_USER, 4), 256, 0, stream>>>(Tbuf, sem_b1, sem_W2, beta, N_USER);

  // out = (beta0*Z[2r] + beta1*Z[2r+1]) @ out_W + out_b, single 128x256 pass
  gemm_out<<<GY_USER, 256, 0, stream>>>(Zsw, WtO, (float*)d_out, out_b, beta);
}

// Round 15
// 383.970 us; speedup vs baseline: 1.0797x; 1.0797x over previous
//
#include <hip/hip_runtime.h>
#include <hip/hip_bf16.h>
#include <math.h>

constexpr int IN_DIM  = 768;
constexpr int HID     = 128;
constexpr int OUT_DIM = 256;
constexpr int SEM     = 512;     // HID*HEADS
constexpr int N_USER  = 50000;
constexpr int N_LLM   = 5000;
constexpr int NE      = 400000;

constexpr int MP_USER = 50048;   // 391*128
constexpr int MP_LLM  = 5120;    // 40*128
constexpr int MP_2U   = 100096;  // 782*128
constexpr int GY_USER = MP_USER / 128;   // 391
constexpr int GY_LLM  = MP_LLM / 128;    // 40

typedef unsigned int uint;
typedef unsigned short ushort;
typedef __attribute__((ext_vector_type(8))) short bf16x8;
typedef __attribute__((ext_vector_type(4))) float f32x4;

constexpr int cdiv(int a, int b) { return (a + b - 1) / b; }

__device__ __forceinline__ ushort f2b(float f) {
  uint u = __float_as_uint(f);
  u += 0x7FFFu + ((u >> 16) & 1u);       // RNE
  return (ushort)(u >> 16);
}
__device__ __forceinline__ float b2f(uint bits16) {
  return __uint_as_float(bits16 << 16);
}

__device__ __forceinline__ float fexp2(float x) { return __builtin_amdgcn_exp2f(x); }
#define LOG2E 1.4426950408889634f

#define GLOAD_LDS16(g, l) __builtin_amdgcn_global_load_lds( \
    (const __attribute__((address_space(1))) void*)(g), \
    (__attribute__((address_space(3))) void*)(l), 16, 0, 0)

// LDS XOR swizzle (T2, rule #21): linear LDS dest (gload_lds), pre-permuted
// GLOBAL source slot; reads XOR slot with (row&7). 16-way conflict -> 2-way.
// Z layout: interleaved — row (2*node + path).

// ---------------- generic bf16 MFMA GEMM (bf16 store) ----------------------
__global__ __launch_bounds__(256) void gemm_bf16_0(
    const ushort* __restrict__ A, const ushort* __restrict__ Bt,
    ushort* __restrict__ Cout, int N, int K)
{
  __shared__ ushort As[128][64];
  __shared__ ushort Bs[128][64];
  const int t = threadIdx.x;
  const int wid = t >> 6, lane = t & 63;

  const int nwg  = gridDim.x * gridDim.y;
  const int orig = blockIdx.y * gridDim.x + blockIdx.x;
  const int q = nwg >> 3, r = nwg & 7;
  const int xcd = orig & 7, idx = orig >> 3;
  const int swz = (xcd < r ? xcd * (q + 1) : r * (q + 1) + (xcd - r) * q) + idx;
  const int bxi = swz % gridDim.x, byi = swz / gridDim.x;

  const int bm = byi * 128, bn = bxi * 128;
  const int lr = lane & 15, kg = lane >> 4;
  const int sw8 = lr & 7;
  const int mbase = (wid >> 1) * 64, nbase = (wid & 1) * 64;
  const int grow = lane >> 3;                         // 0..7
  const int gcol = (((lane & 7) ^ grow)) * 8;         // pre-swizzled source slot

  f32x4 acc[4][4] = {};

  for (int k0 = 0; k0 < K; k0 += 64) {
#pragma unroll
    for (int c = 0; c < 4; ++c) {
      int ch = wid * 4 + c;
      GLOAD_LDS16(A  + (size_t)(bm + ch * 8 + grow) * K + k0 + gcol, &As[ch * 8][0]);
      GLOAD_LDS16(Bt + (size_t)(bn + ch * 8 + grow) * K + k0 + gcol, &Bs[ch * 8][0]);
    }
    asm volatile("s_waitcnt vmcnt(0)" ::: "memory");
    __syncthreads();
#pragma unroll
    for (int kb = 0; kb < 2; ++kb) {
      const int csw = ((kb * 4 + kg) ^ sw8) * 8;      // swizzled read slot
      bf16x8 av[4], bv[4];
#pragma unroll
      for (int m = 0; m < 4; ++m)
        av[m] = *(const bf16x8*)&As[mbase + m * 16 + lr][csw];
#pragma unroll
      for (int n = 0; n < 4; ++n)
        bv[n] = *(const bf16x8*)&Bs[nbase + n * 16 + lr][csw];
#pragma unroll
      for (int m = 0; m < 4; ++m)
#pragma unroll
        for (int n = 0; n < 4; ++n)
          acc[m][n] = __builtin_amdgcn_mfma_f32_16x16x32_bf16(av[m], bv[n], acc[m][n], 0, 0, 0);
    }
    __syncthreads();
  }

#pragma unroll
  for (int m = 0; m < 4; ++m)
#pragma unroll
    for (int j = 0; j < 4; ++j) {
      int row = bm + mbase + m * 16 + kg * 4 + j;
#pragma unroll
      for (int n = 0; n < 4; ++n) {
        int col = bn + nbase + n * 16 + lr;
        Cout[(size_t)row * N + col] = f2b(acc[m][n][j]);
      }
    }
}

// ------------- merged hs GEMM (user + llm) with fused logit columns --------
// Grid (5, GY_USER+GY_LLM). N=640: col tiles 0..3 -> bf16 hs (stride 512),
// col tile 4 -> fp32 logit[row][16]. acc[4][4], VGPR ~96, 32KB LDS (R13 cfg).
__global__ __launch_bounds__(256) void gemm_hs(
    const ushort* __restrict__ A_u, const ushort* __restrict__ A_l,
    const ushort* __restrict__ Bt_u, const ushort* __restrict__ Bt_l,
    ushort* __restrict__ hs_u, ushort* __restrict__ hs_l,
    float* __restrict__ logU, float* __restrict__ logL)
{
  __shared__ ushort As[128][64];
  __shared__ ushort Bs[128][64];
  const int t = threadIdx.x;
  const int wid = t >> 6, lane = t & 63;
  const int K = IN_DIM;

  const int nwg  = gridDim.x * gridDim.y;
  const int orig = blockIdx.y * gridDim.x + blockIdx.x;
  const int q = nwg >> 3, r = nwg & 7;
  const int xcd = orig & 7, idx = orig >> 3;
  const int swz = (xcd < r ? xcd * (q + 1) : r * (q + 1) + (xcd - r) * q) + idx;
  const int bxi = swz % gridDim.x, byi0 = swz / gridDim.x;

  const bool llm = (byi0 >= GY_USER);
  const int byi = llm ? byi0 - GY_USER : byi0;
  const ushort* A    = llm ? A_l : A_u;
  const ushort* Bt   = llm ? Bt_l : Bt_u;
  ushort* hs         = llm ? hs_l : hs_u;
  float* logit       = llm ? logL : logU;

  const int bm = byi * 128, bn = bxi * 128;
  const int lr = lane & 15, kg = lane >> 4;
  const int sw8 = lr & 7;
  const int mbase = (wid >> 1) * 64, nbase = (wid & 1) * 64;
  const int grow = lane >> 3;
  const int gcol = (((lane & 7) ^ grow)) * 8;

  f32x4 acc[4][4] = {};

  for (int k0 = 0; k0 < K; k0 += 64) {
#pragma unroll
    for (int c = 0; c < 4; ++c) {
      int ch = wid * 4 + c;
      GLOAD_LDS16(A  + (size_t)(bm + ch * 8 + grow) * K + k0 + gcol, &As[ch * 8][0]);
      GLOAD_LDS16(Bt + (size_t)(bn + ch * 8 + grow) * K + k0 + gcol, &Bs[ch * 8][0]);
    }
    asm volatile("s_waitcnt vmcnt(0)" ::: "memory");
    __syncthreads();
#pragma unroll
    for (int kb = 0; kb < 2; ++kb) {
      const int csw = ((kb * 4 + kg) ^ sw8) * 8;
      bf16x8 av[4], bv[4];
#pragma unroll
      for (int m = 0; m < 4; ++m)
        av[m] = *(const bf16x8*)&As[mbase + m * 16 + lr][csw];
#pragma unroll
      for (int n = 0; n < 4; ++n)
        bv[n] = *(const bf16x8*)&Bs[nbase + n * 16 + lr][csw];
#pragma unroll
      for (int m = 0; m < 4; ++m)
#pragma unroll
        for (int n = 0; n < 4; ++n)
          acc[m][n] = __builtin_amdgcn_mfma_f32_16x16x32_bf16(av[m], bv[n], acc[m][n], 0, 0, 0);
    }
    __syncthreads();
  }

  if (bxi == (int)gridDim.x - 1) {
    if (nbase == 0) {
#pragma unroll
      for (int m = 0; m < 4; ++m)
#pragma unroll
        for (int j = 0; j < 4; ++j) {
          int row = bm + mbase + m * 16 + kg * 4 + j;
          logit[(size_t)row * 16 + lr] = acc[m][0][j];
        }
    }
    return;
  }

#pragma unroll
  for (int m = 0; m < 4; ++m)
#pragma unroll
    for (int j = 0; j < 4; ++j) {
      int row = bm + mbase + m * 16 + kg * 4 + j;
#pragma unroll
      for (int n = 0; n < 4; ++n) {
        int col = bn + nbase + n * 16 + lr;
        hs[(size_t)row * SEM + col] = f2b(acc[m][n][j]);
      }
    }
}

// ------------- fused combine + out GEMM: 128x256 tile, single N pass -------
// A synthesized as beta.x*Z[2*row] + beta.y*Z[2*row+1] (interleaved layout).
__global__ __launch_bounds__(256) void gemm_out(
    const ushort* __restrict__ Z, const ushort* __restrict__ WtO,
    float* __restrict__ out, const float* __restrict__ out_b,
    const float2* __restrict__ beta)
{
  __shared__ ushort As[128][64];   // 16 KB
  __shared__ ushort Bs[256][64];   // 32 KB
  const int t = threadIdx.x;
  const int wid = t >> 6, lane = t & 63;
  const int K = SEM;

  const int nwg  = gridDim.x;
  const int orig = blockIdx.x;
  const int q = nwg >> 3, r = nwg & 7;
  const int xcd = orig & 7, idx = orig >> 3;
  const int swz = (xcd < r ? xcd * (q + 1) : r * (q + 1) + (xcd - r) * q) + idx;

  const int bm = swz * 128;
  const int lr = lane & 15, kg = lane >> 4;
  const int sw8 = lr & 7;
  const int mbase = (wid >> 1) * 64, nbase = (wid & 1) * 128;
  const int grow = lane >> 3;
  const int gcol = (((lane & 7) ^ grow)) * 8;
  const int wcol = (((lane & 7) ^ grow)) * 8;   // swizzled ds_write slot

  f32x4 acc[4][8] = {};

  for (int k0 = 0; k0 < K; k0 += 64) {
#pragma unroll
    for (int c = 0; c < 8; ++c) {
      int ch = wid * 8 + c;            // 0..31
      GLOAD_LDS16(WtO + (size_t)(ch * 8 + grow) * K + k0 + gcol, &Bs[ch * 8][0]);
    }
#pragma unroll
    for (int c = 0; c < 4; ++c) {
      int ch = wid * 4 + c;
      int rl = ch * 8 + grow;          // 0..127 ; rl&7 == grow
      int row = bm + rl;
      const ushort* z0p = Z + (size_t)(2 * row) * SEM + k0 + (lane & 7) * 8;
      const ushort* z1p = z0p + SEM;
      float2 bb = beta[row];
      uint4 a0 = *(const uint4*)z0p;
      uint4 a1 = *(const uint4*)z1p;
      uint rpk[4];
#pragma unroll
      for (int qq = 0; qq < 4; ++qq) {
        uint x0 = ((const uint*)&a0)[qq], x1 = ((const uint*)&a1)[qq];
        float lo = bb.x * b2f(x0 & 0xffffu) + bb.y * b2f(x1 & 0xffffu);
        float hi = bb.x * b2f(x0 >> 16)     + bb.y * b2f(x1 >> 16);
        rpk[qq] = (uint)f2b(lo) | ((uint)f2b(hi) << 16);
      }
      *(uint4*)&As[rl][wcol] = make_uint4(rpk[0], rpk[1], rpk[2], rpk[3]);
    }
    asm volatile("s_waitcnt vmcnt(0)" ::: "memory");
    __syncthreads();
#pragma unroll
    for (int kb = 0; kb < 2; ++kb) {
      const int csw = ((kb * 4 + kg) ^ sw8) * 8;
      bf16x8 av[4], bv[8];
#pragma unroll
      for (int m = 0; m < 4; ++m)
        av[m] = *(const bf16x8*)&As[mbase + m * 16 + lr][csw];
#pragma unroll
      for (int n = 0; n < 8; ++n)
        bv[n] = *(const bf16x8*)&Bs[nbase + n * 16 + lr][csw];
#pragma unroll
      for (int m = 0; m < 4; ++m)
#pragma unroll
        for (int n = 0; n < 8; ++n)
          acc[m][n] = __builtin_amdgcn_mfma_f32_16x16x32_bf16(av[m], bv[n], acc[m][n], 0, 0, 0);
    }
    __syncthreads();
  }

#pragma unroll
  for (int m = 0; m < 4; ++m)
#pragma unroll
    for (int j = 0; j < 4; ++j) {
      int row = bm + mbase + m * 16 + kg * 4 + j;
      if (row >= N_USER) continue;
#pragma unroll
      for (int n = 0; n < 8; ++n) {
        int col = nbase + n * 16 + lr;
        out[(size_t)row * OUT_DIM + col] = acc[m][n][j] + out_b[col];
      }
    }
}

// ---------------- mega prep kernel (grid-strided) --------------------------
constexpr int NB_FOLD  = cdiv(IN_DIM * 16, 256);            // 48
constexpr int NB_CASTU = N_USER * IN_DIM / 8 / 256;         // 18750
constexpr int NB_CASTL = N_LLM * IN_DIM / 8 / 256;          // 1875
constexpr int NB_TTW   = (IN_DIM / 64) * (SEM / 64);        // 96 (x2)
constexpr int NB_TTS   = (SEM / 64) * (HID / 64);           // 16
constexpr int NB_TTO   = (SEM / 64) * (OUT_DIM / 64);       // 32
constexpr int NB_E1    = cdiv(2 * NE, 256);                 // 3125
constexpr int PB0 = NB_FOLD;
constexpr int PB1 = PB0 + NB_CASTU;
constexpr int PB2 = PB1 + NB_CASTL;
constexpr int PB3 = PB2 + NB_TTW;
constexpr int PB4 = PB3 + NB_TTW;
constexpr int PB5 = PB4 + NB_TTS;
constexpr int PB6 = PB5 + NB_TTO;
constexpr int PB7 = PB6 + NB_E1;
constexpr int PREP_GRID = 2048;

// LDS-tiled transpose-cast: W fp32 [K][Nw] -> Bt bf16 [Nw][K], 64x64 tile.
__device__ __forceinline__ void tt_body(const float* __restrict__ W,
                                        ushort* __restrict__ Bt,
                                        int K, int Nw, int tile,
                                        float (*lds)[65], int t)
{
  const int tiles_n = Nw >> 6;
  const int tk = tile / tiles_n, tn = tile - tk * tiles_n;
  const int k0 = tk << 6, n0 = tn << 6;
#pragma unroll
  for (int i = 0; i < 16; ++i) {
    int idx = t + i * 256;
    int rr = idx >> 6, cc = idx & 63;
    lds[rr][cc] = W[(size_t)(k0 + rr) * Nw + n0 + cc];
  }
  __syncthreads();
#pragma unroll
  for (int i = 0; i < 4; ++i) {
    int idx = t + i * 256;                 // 0..1023
    int cc = idx >> 4;                     // 0..63 (output row = n0+cc)
    int rq = (idx & 15) * 4;               // 0,4,...,60
    uint lo = (uint)f2b(lds[rq][cc])     | ((uint)f2b(lds[rq + 1][cc]) << 16);
    uint hi = (uint)f2b(lds[rq + 2][cc]) | ((uint)f2b(lds[rq + 3][cc]) << 16);
    *(uint2*)(Bt + (size_t)(n0 + cc) * K + k0 + rq) = make_uint2(lo, hi);
  }
  __syncthreads();
}

__device__ __forceinline__ void cast_body(const float* __restrict__ x,
                                          ushort* __restrict__ xb, int i)
{
  const float4 a = *(const float4*)(x + (size_t)i * 8);
  const float4 c = *(const float4*)(x + (size_t)i * 8 + 4);
  uint4 o;
  o.x = (uint)f2b(a.x) | ((uint)f2b(a.y) << 16);
  o.y = (uint)f2b(a.z) | ((uint)f2b(a.w) << 16);
  o.z = (uint)f2b(c.x) | ((uint)f2b(c.y) << 16);
  o.w = (uint)f2b(c.z) | ((uint)f2b(c.w) << 16);
  *(uint4*)(xb + (size_t)i * 8) = o;
}

__global__ __launch_bounds__(256) void prep_kernel(
    const float* __restrict__ x_user, const float* __restrict__ x_llm,
    ushort* __restrict__ xb_u, ushort* __restrict__ xb_l,
    const float* __restrict__ Wdst0, const float* __restrict__ adst0,
    const float* __restrict__ Wdst1, const float* __restrict__ adst1,
    const float* __restrict__ Wsrc1, const float* __restrict__ asrc1,
    const float* __restrict__ Wsrc0, const float* __restrict__ asrc0,
    ushort* __restrict__ Wt1x, ushort* __restrict__ Wt0x,
    const float* __restrict__ sem_W1, ushort* __restrict__ WtS,
    const float* __restrict__ out_W, ushort* __restrict__ WtO,
    const int* __restrict__ dst0, const int* __restrict__ dst1,
    int* __restrict__ deg, int* __restrict__ rank)
{
  __shared__ float lds[64][65];   // 16.6 KB, used by transpose sections
  const int t = threadIdx.x;
  for (int b = blockIdx.x; b < PB7; b += PREP_GRID) {
    if (b < PB0) {
      int idxg = b * 256 + t;
      if (idxg < IN_DIM * 16) {
        int k = idxg >> 4, hh = idxg & 15;
        const float* W;
        const float* att;
        if (hh < 4)       { W = Wdst0; att = adst0; }
        else if (hh < 8)  { W = Wdst1; att = adst1; }
        else if (hh < 12) { W = Wsrc1; att = asrc1; }
        else              { W = Wsrc0; att = asrc0; }
        int h = hh & 3;
        float s = 0.f;
#pragma unroll 4
        for (int c = 0; c < HID; ++c)
          s += W[(size_t)k * SEM + h * HID + c] * att[h * HID + c];
        if (hh < 12) Wt1x[(size_t)(512 + hh) * IN_DIM + k] = f2b(s);
        else         Wt0x[(size_t)(512 + h) * IN_DIM + k] = f2b(s);
      }
    } else if (b < PB1) {
      cast_body(x_user, xb_u, (b - PB0) * 256 + t);
    } else if (b < PB2) {
      cast_body(x_llm, xb_l, (b - PB1) * 256 + t);
    } else if (b < PB3) {
      tt_body(Wsrc0, Wt0x, IN_DIM, SEM, b - PB2, lds, t);
    } else if (b < PB4) {
      tt_body(Wsrc1, Wt1x, IN_DIM, SEM, b - PB3, lds, t);
    } else if (b < PB5) {
      tt_body(sem_W1, WtS, SEM, HID, b - PB4, lds, t);
    } else if (b < PB6) {
      tt_body(out_W, WtO, SEM, OUT_DIM, b - PB5, lds, t);
    } else {
      int e = (b - PB6) * 256 + t;
      if (e < 2 * NE) {
        int d = (e < NE) ? dst0[e] : (dst1[e - NE] + N_USER);
        rank[e] = atomicAdd(&deg[d], 1);
      }
    }
  }
}

// -------- scatter src (ushort) into CSR slots — atomic-free, grid-strided --
__global__ void scatter_kernel(const int* __restrict__ src0, const int* __restrict__ dst0,
                               const int* __restrict__ src1, const int* __restrict__ dst1,
                               const int* __restrict__ rp, const int* __restrict__ rank,
                               ushort* __restrict__ scsr)
{
  for (int e = blockIdx.x * 256 + threadIdx.x; e < 2 * NE; e += gridDim.x * 256) {
    bool p1 = (e >= NE);
    int ee = p1 ? e - NE : e;
    int s = p1 ? src1[ee] : src0[ee];
    int d = p1 ? (dst1[ee] + N_USER) : dst0[ee];
    scsr[rp[d] + rank[e]] = (ushort)s;
  }
}

// -------- 3-phase scan over deg[0..n) --------------------------------------
__global__ __launch_bounds__(256) void scan1(const int* __restrict__ deg,
                                             int* __restrict__ bsum, int n)
{
  __shared__ int sm[256];
  int b = blockIdx.x, t = threadIdx.x;
  int base = b * 1024 + t * 4;
  int s = 0;
#pragma unroll
  for (int i = 0; i < 4; ++i) if (base + i < n) s += deg[base + i];
  sm[t] = s;
  __syncthreads();
  for (int off = 128; off > 0; off >>= 1) {
    if (t < off) sm[t] += sm[t + off];
    __syncthreads();
  }
  if (t == 0) bsum[b] = sm[0];
}

__global__ __launch_bounds__(128) void scan2(const int* __restrict__ bsum,
                                             int* __restrict__ boff, int nb,
                                             int* __restrict__ rp_tail, int tailval)
{
  __shared__ int sm[128];
  int t = threadIdx.x;
  int v = (t < nb) ? bsum[t] : 0;
  sm[t] = v;
  __syncthreads();
  for (int off = 1; off < 128; off <<= 1) {
    int x = (t >= off) ? sm[t - off] : 0;
    __syncthreads();
    sm[t] += x;
    __syncthreads();
  }
  if (t < nb) boff[t] = sm[t] - v;
  if (t == 0) *rp_tail = tailval;
}

__global__ __launch_bounds__(256) void scan3(const int* __restrict__ deg,
                                             const int* __restrict__ boff,
                                             int* __restrict__ rp, int n)
{
  __shared__ int sm[256];
  int b = blockIdx.x, t = threadIdx.x;
  int base = b * 1024 + t * 4;
  int v[4];
#pragma unroll
  for (int i = 0; i < 4; ++i) v[i] = (base + i < n) ? deg[base + i] : 0;
  int tsum = v[0] + v[1] + v[2] + v[3];
  sm[t] = tsum;
  __syncthreads();
  for (int off = 1; off < 256; off <<= 1) {
    int x = (t >= off) ? sm[t - off] : 0;
    __syncthreads();
    sm[t] += x;
    __syncthreads();
  }
  int run = sm[t] - tsum + boff[b];
#pragma unroll
  for (int i = 0; i < 4; ++i) {
    if (base + i < n) rp[base + i] = run;
    run += v[i];
  }
}

// -------- unified aggregation: ONE WAVE per dst node -----------------------
// Writes Z in interleaved layout: row = 2*nd + path.
__global__ __launch_bounds__(64) void agg_kernel(
    const ushort* __restrict__ hs0, const ushort* __restrict__ hs1,
    const ushort* __restrict__ srcs,
    const float* __restrict__ logitL, const float* __restrict__ logitU,
    const int* __restrict__ rp,
    const float* __restrict__ bias0, const float* __restrict__ bias1,
    ushort* __restrict__ Zout)
{
  __shared__ ushort s_src[64];
  __shared__ float  s_ev[64][4];
  int node = blockIdx.x, lane = threadIdx.x;
  bool p1 = (node >= N_USER);
  const ushort* hs   = p1 ? hs1 : hs0;
  const float*  bias = p1 ? bias1 : bias0;
  int nd = p1 ? node - N_USER : node;
  float4 ad4 = *(const float4*)(logitU + (size_t)nd * 16 + (p1 ? 4 : 0));
  ad4.x *= LOG2E; ad4.y *= LOG2E; ad4.z *= LOG2E; ad4.w *= LOG2E;
  const float* asbase = p1 ? (logitU + 8) : logitL;
  int h  = lane >> 4;
  int cb = lane * 8;
  float acc[8] = {};
  float dsum = 0.f;
  int jb = rp[node], je = rp[node + 1];
  for (int j0 = jb; j0 < je; j0 += 64) {
    int n = min(64, je - j0);
    __syncthreads();
    if (lane < n) {
      int s = srcs[j0 + lane];
      s_src[lane] = (ushort)s;
      float4 as4 = *(const float4*)(asbase + (size_t)s * 16);
      float v0 = as4.x * LOG2E + ad4.x, v1 = as4.y * LOG2E + ad4.y;
      float v2 = as4.z * LOG2E + ad4.z, v3 = as4.w * LOG2E + ad4.w;
      v0 = (v0 > 0.f) ? v0 : 0.2f * v0;
      v1 = (v1 > 0.f) ? v1 : 0.2f * v1;
      v2 = (v2 > 0.f) ? v2 : 0.2f * v2;
      v3 = (v3 > 0.f) ? v3 : 0.2f * v3;
      s_ev[lane][0] = fexp2(v0);
      s_ev[lane][1] = fexp2(v1);
      s_ev[lane][2] = fexp2(v2);
      s_ev[lane][3] = fexp2(v3);
    }
    __syncthreads();
#pragma unroll 4
    for (int j = 0; j < n; ++j) {
      int s = __builtin_amdgcn_readfirstlane((int)s_src[j]);
      float e = s_ev[j][h];
      const uint4 pv = *(const uint4*)(hs + ((size_t)s << 9) + cb);
      acc[0] += b2f(pv.x & 0xffffu) * e;  acc[1] += b2f(pv.x >> 16) * e;
      acc[2] += b2f(pv.y & 0xffffu) * e;  acc[3] += b2f(pv.y >> 16) * e;
      acc[4] += b2f(pv.z & 0xffffu) * e;  acc[5] += b2f(pv.z >> 16) * e;
      acc[6] += b2f(pv.w & 0xffffu) * e;  acc[7] += b2f(pv.w >> 16) * e;
      dsum += e;
    }
  }
  float inv = 1.f / (dsum + 1e-16f);
  float4 b4a = *(const float4*)(bias + cb);
  float4 b4b = *(const float4*)(bias + cb + 4);
  float bb[8] = { b4a.x, b4a.y, b4a.z, b4a.w, b4b.x, b4b.y, b4b.z, b4b.w };
  uint4 o;
  uint* op = (uint*)&o;
#pragma unroll
  for (int i = 0; i < 4; ++i) {
    float z0 = acc[2 * i]     * inv + bb[2 * i];
    float z1 = acc[2 * i + 1] * inv + bb[2 * i + 1];
    z0 = (z0 > 0.f) ? z0 : fexp2(z0 * LOG2E) - 1.f;
    z1 = (z1 > 0.f) ? z1 : fexp2(z1 * LOG2E) - 1.f;
    op[i] = (uint)f2b(z0) | ((uint)f2b(z1) << 16);
  }
  int zrow = 2 * nd + (p1 ? 1 : 0);
  *(uint4*)(Zout + (size_t)zrow * SEM + cb) = o;
}

// -------- beta: semantic softmax weights per node (wave per node) ----------
// T rows interleaved: node's two paths at rows 2*node, 2*node+1.
__global__ __launch_bounds__(256) void beta_kernel(
    const ushort* __restrict__ T, const float* __restrict__ b1,
    const float* __restrict__ W2, float2* __restrict__ beta, int n)
{
  int wid = threadIdx.x >> 6, lane = threadIdx.x & 63;
  int node = blockIdx.x * 4 + wid;
  if (node >= n) return;
  const ushort* t0 = T + (size_t)(2 * node) * HID;
  const ushort* t1 = t0 + HID;
  int j = 2 * lane;
  uint u0 = *(const uint*)(t0 + j);
  uint u1 = *(const uint*)(t1 + j);
  float wa = W2[j], wb = W2[j + 1];
  float ba = b1[j], bb = b1[j + 1];
  auto ftanh = [](float x) {
    x = fminf(fmaxf(x, -20.f), 20.f);
    float e = fexp2(2.f * LOG2E * x);
    return (e - 1.f) / (e + 1.f);
  };
  float s0 = ftanh(b2f(u0 & 0xffffu) + ba) * wa + ftanh(b2f(u0 >> 16) + bb) * wb;
  float s1 = ftanh(b2f(u1 & 0xffffu) + ba) * wa + ftanh(b2f(u1 >> 16) + bb) * wb;
#pragma unroll
  for (int off = 32; off > 0; off >>= 1) {
    s0 += __shfl_down(s0, off);
    s1 += __shfl_down(s1, off);
  }
  if (lane == 0) {
    float mx = fmaxf(s0, s1);
    float e0 = fexp2((s0 - mx) * LOG2E), e1 = fexp2((s1 - mx) * LOG2E);
    float s = e0 + e1;
    beta[node] = make_float2(e0 / s, e1 / s);
  }
}

extern "C" void kernel_launch(void* const* d_in, const int* in_sizes, int n_in,
                              void* d_out, int out_size, void* d_ws, size_t ws_size,
                              hipStream_t stream)
{
  const float* x_user = (const float*)d_in[0];
  const float* x_llm  = (const float*)d_in[1];
  const int* src0 = (const int*)d_in[2];
  const int* dst0 = (const int*)d_in[3];
  const int* src1 = (const int*)d_in[4];
  const int* dst1 = (const int*)d_in[5];
  const float* Wsrc0 = (const float*)d_in[6];
  const float* Wdst0 = (const float*)d_in[7];
  const float* asrc0 = (const float*)d_in[8];
  const float* adst0 = (const float*)d_in[9];
  const float* bias0 = (const float*)d_in[10];
  const float* Wsrc1 = (const float*)d_in[11];
  const float* Wdst1 = (const float*)d_in[12];
  const float* asrc1 = (const float*)d_in[13];
  const float* adst1 = (const float*)d_in[14];
  const float* bias1 = (const float*)d_in[15];
  const float* sem_W1 = (const float*)d_in[16];
  const float* sem_b1 = (const float*)d_in[17];
  const float* sem_W2 = (const float*)d_in[18];
  const float* out_W  = (const float*)d_in[19];
  const float* out_b  = (const float*)d_in[20];

  char* ws = (char*)d_ws;
  size_t off = 0;
  auto alloc = [&](size_t bytes) -> size_t {
    size_t o = off;
    off += (bytes + 255) & ~(size_t)255;
    return o;
  };

  size_t xbu_off  = alloc((size_t)MP_USER * IN_DIM * 2);   // later overlaid by T bf16
  size_t xbl_off  = alloc((size_t)MP_LLM  * IN_DIM * 2);
  size_t wt0_off  = alloc((size_t)640 * IN_DIM * 2);
  size_t wt1_off  = alloc((size_t)640 * IN_DIM * 2);
  size_t wts_off  = alloc((size_t)HID * SEM * 2);
  size_t wto_off  = alloc((size_t)OUT_DIM * SEM * 2);
  size_t hs0_off  = alloc((size_t)MP_LLM  * SEM * 2);
  size_t hs1_off  = alloc((size_t)MP_USER * SEM * 2);
  size_t Z_off    = alloc((size_t)MP_2U   * SEM * 2);
  size_t sc_off   = alloc((size_t)2 * NE * 2);
  size_t rank_off = alloc((size_t)2 * NE * 4);
  size_t lgu_off  = alloc((size_t)MP_USER * 16 * 4);
  size_t lgl_off  = alloc((size_t)MP_LLM  * 16 * 4);
  size_t beta_off = alloc((size_t)MP_USER * 8);
  size_t deg_off  = alloc((size_t)2 * N_USER * 4);         // zeroed
  size_t zero_end = off;
  size_t rp_off   = alloc((size_t)(2 * N_USER + 1) * 4);
  size_t bs_off   = alloc((size_t)128 * 4);
  size_t bo_off   = alloc((size_t)128 * 4);

  ushort* xb_u  = (ushort*)(ws + xbu_off);
  ushort* xb_l  = (ushort*)(ws + xbl_off);
  ushort* Wt0x  = (ushort*)(ws + wt0_off);
  ushort* Wt1x  = (ushort*)(ws + wt1_off);
  ushort* WtS   = (ushort*)(ws + wts_off);
  ushort* WtO   = (ushort*)(ws + wto_off);
  ushort* hs0b  = (ushort*)(ws + hs0_off);
  ushort* hs1b  = (ushort*)(ws + hs1_off);
  ushort* Zsw   = (ushort*)(ws + Z_off);
  ushort* Tbuf  = (ushort*)(ws + xbu_off);  // overlay: xb dead after hs GEMMs
  ushort* scsr  = (ushort*)(ws + sc_off);
  int*    rank  = (int*)(ws + rank_off);
  float*  logU  = (float*)(ws + lgu_off);
  float*  logL  = (float*)(ws + lgl_off);
  float2* beta  = (float2*)(ws + beta_off);
  int*    deg   = (int*)(ws + deg_off);
  int*    rp    = (int*)(ws + rp_off);
  int*    bsum  = (int*)(ws + bs_off);
  int*    boff  = (int*)(ws + bo_off);

  hipMemsetAsync(ws + deg_off, 0, zero_end - deg_off, stream);
  hipMemsetAsync(Wt0x + (size_t)512 * IN_DIM, 0, (size_t)128 * IN_DIM * 2, stream);
  hipMemsetAsync(Wt1x + (size_t)512 * IN_DIM, 0, (size_t)128 * IN_DIM * 2, stream);

  // mega prep (grid-strided): fold + casts + tiled transposes + degree/rank
  prep_kernel<<<PREP_GRID, 256, 0, stream>>>(
      x_user, x_llm, xb_u, xb_l,
      Wdst0, adst0, Wdst1, adst1, Wsrc1, asrc1, Wsrc0, asrc0,
      Wt1x, Wt0x, sem_W1, WtS, out_W, WtO,
      dst0, dst1, deg, rank);

  // CSR build over unified node space
  const int NTOT = 2 * N_USER;
  const int NB = cdiv(NTOT, 1024);   // 98
  scan1<<<NB, 256, 0, stream>>>(deg, bsum, NTOT);
  scan2<<<1, 128, 0, stream>>>(bsum, boff, NB, rp + NTOT, 2 * NE);
  scan3<<<NB, 256, 0, stream>>>(deg, boff, rp, NTOT);
  scatter_kernel<<<2048, 256, 0, stream>>>(src0, dst0, src1, dst1, rp, rank, scsr);

  // merged hs GEMMs (5 col-tiles: 4x128 hs + 1 logit) — R13 config
  {
    dim3 g(640 / 128, GY_USER + GY_LLM);
    gemm_hs<<<g, 256, 0, stream>>>(xb_u, xb_l, Wt1x, Wt0x, hs1b, hs0b, logU, logL);
  }

  // unified aggregation (one wave per node) -> bf16 Z (interleaved rows)
  agg_kernel<<<NTOT, 64, 0, stream>>>(hs0b, hs1b, scsr, logL, logU, rp,
                                      bias0, bias1, Zsw);

  // T = Z @ sem_W1 (bf16 out, overlays dead xb_u; rows interleaved like Z)
  {
    dim3 g(HID / 128, MP_2U / 128);
    gemm_bf16_0<<<g, 256, 0, stream>>>(Zsw, WtS, Tbuf, HID, SEM);
  }

  // semantic softmax weights (interleaved T rows)
  beta_kernel<<<cdiv(N_USER, 4), 256, 0, stream>>>(Tbuf, sem_b1, sem_W2, beta, N_USER);

  // out = (beta0*Z[2r] + beta1*Z[2r+1]) @ out_W + out_b, single 128x256 pass
  gemm_out<<<GY_USER, 256, 0, stream>>>(Zsw, WtO, (float*)d_out, out_b, beta);
}

// Round 16
// 379.130 us; speedup vs baseline: 1.0935x; 1.0128x over previous
//
#include <hip/hip_runtime.h>
#include <hip/hip_bf16.h>
#include <math.h>

constexpr int IN_DIM  = 768;
constexpr int HID     = 128;
constexpr int OUT_DIM = 256;
constexpr int SEM     = 512;     // HID*HEADS
constexpr int N_USER  = 50000;
constexpr int N_LLM   = 5000;
constexpr int NE      = 400000;

constexpr int MP_USER = 50048;   // 391*128
constexpr int MP_LLM  = 5120;    // 40*128
constexpr int MP_2U   = 100096;  // 782*128
constexpr int GY_USER = MP_USER / 128;   // 391
constexpr int GY_LLM  = MP_LLM / 128;    // 40

typedef unsigned int uint;
typedef unsigned short ushort;
typedef __attribute__((ext_vector_type(8))) short bf16x8;
typedef __attribute__((ext_vector_type(4))) float f32x4;

constexpr int cdiv(int a, int b) { return (a + b - 1) / b; }

__device__ __forceinline__ ushort f2b(float f) {
  uint u = __float_as_uint(f);
  u += 0x7FFFu + ((u >> 16) & 1u);       // RNE
  return (ushort)(u >> 16);
}
__device__ __forceinline__ float b2f(uint bits16) {
  return __uint_as_float(bits16 << 16);
}

__device__ __forceinline__ float fexp2(float x) { return __builtin_amdgcn_exp2f(x); }
#define LOG2E 1.4426950408889634f

#define GLOAD_LDS16(g, l) __builtin_amdgcn_global_load_lds( \
    (const __attribute__((address_space(1))) void*)(g), \
    (__attribute__((address_space(3))) void*)(l), 16, 0, 0)

// LDS XOR swizzle (T2, rule #21): linear LDS dest (gload_lds), pre-permuted
// GLOBAL source slot; reads XOR slot with (row&7). 16-way conflict -> 2-way.
// Z layout: interleaved — row (2*node + path).

// ------------- merged hs GEMM (user + llm) with fused logit columns --------
// Grid (5, GY_USER+GY_LLM). N=640: col tiles 0..3 -> bf16 hs (stride 512),
// col tile 4 -> fp32 logit[row][16]. acc[4][4], VGPR ~96, 32KB LDS.
__global__ __launch_bounds__(256) void gemm_hs(
    const ushort* __restrict__ A_u, const ushort* __restrict__ A_l,
    const ushort* __restrict__ Bt_u, const ushort* __restrict__ Bt_l,
    ushort* __restrict__ hs_u, ushort* __restrict__ hs_l,
    float* __restrict__ logU, float* __restrict__ logL)
{
  __shared__ ushort As[128][64];
  __shared__ ushort Bs[128][64];
  const int t = threadIdx.x;
  const int wid = t >> 6, lane = t & 63;
  const int K = IN_DIM;

  const int nwg  = gridDim.x * gridDim.y;
  const int orig = blockIdx.y * gridDim.x + blockIdx.x;
  const int q = nwg >> 3, r = nwg & 7;
  const int xcd = orig & 7, idx = orig >> 3;
  const int swz = (xcd < r ? xcd * (q + 1) : r * (q + 1) + (xcd - r) * q) + idx;
  const int bxi = swz % gridDim.x, byi0 = swz / gridDim.x;

  const bool llm = (byi0 >= GY_USER);
  const int byi = llm ? byi0 - GY_USER : byi0;
  const ushort* A    = llm ? A_l : A_u;
  const ushort* Bt   = llm ? Bt_l : Bt_u;
  ushort* hs         = llm ? hs_l : hs_u;
  float* logit       = llm ? logL : logU;

  const int bm = byi * 128, bn = bxi * 128;
  const int lr = lane & 15, kg = lane >> 4;
  const int sw8 = lr & 7;
  const int mbase = (wid >> 1) * 64, nbase = (wid & 1) * 64;
  const int grow = lane >> 3;
  const int gcol = (((lane & 7) ^ grow)) * 8;

  f32x4 acc[4][4] = {};

  for (int k0 = 0; k0 < K; k0 += 64) {
#pragma unroll
    for (int c = 0; c < 4; ++c) {
      int ch = wid * 4 + c;
      GLOAD_LDS16(A  + (size_t)(bm + ch * 8 + grow) * K + k0 + gcol, &As[ch * 8][0]);
      GLOAD_LDS16(Bt + (size_t)(bn + ch * 8 + grow) * K + k0 + gcol, &Bs[ch * 8][0]);
    }
    asm volatile("s_waitcnt vmcnt(0)" ::: "memory");
    __syncthreads();
#pragma unroll
    for (int kb = 0; kb < 2; ++kb) {
      const int csw = ((kb * 4 + kg) ^ sw8) * 8;
      bf16x8 av[4], bv[4];
#pragma unroll
      for (int m = 0; m < 4; ++m)
        av[m] = *(const bf16x8*)&As[mbase + m * 16 + lr][csw];
#pragma unroll
      for (int n = 0; n < 4; ++n)
        bv[n] = *(const bf16x8*)&Bs[nbase + n * 16 + lr][csw];
#pragma unroll
      for (int m = 0; m < 4; ++m)
#pragma unroll
        for (int n = 0; n < 4; ++n)
          acc[m][n] = __builtin_amdgcn_mfma_f32_16x16x32_bf16(av[m], bv[n], acc[m][n], 0, 0, 0);
    }
    __syncthreads();
  }

  if (bxi == (int)gridDim.x - 1) {
    if (nbase == 0) {
#pragma unroll
      for (int m = 0; m < 4; ++m)
#pragma unroll
        for (int j = 0; j < 4; ++j) {
          int row = bm + mbase + m * 16 + kg * 4 + j;
          logit[(size_t)row * 16 + lr] = acc[m][0][j];
        }
    }
    return;
  }

#pragma unroll
  for (int m = 0; m < 4; ++m)
#pragma unroll
    for (int j = 0; j < 4; ++j) {
      int row = bm + mbase + m * 16 + kg * 4 + j;
#pragma unroll
      for (int n = 0; n < 4; ++n) {
        int col = bn + nbase + n * 16 + lr;
        hs[(size_t)row * SEM + col] = f2b(acc[m][n][j]);
      }
    }
}

// ------------- fused T-GEMM + semantic softmax -> beta ---------------------
// T = Z @ WtS^T computed per 128-row tile (64 nodes, interleaved paths), then
// w[row] = sum_col tanh(T+b1)*W2 reduced in-register + LDS; beta = softmax2.
// T is never materialized. Grid: MP_2U/128 = 782 blocks.
__global__ __launch_bounds__(256) void gemm_beta(
    const ushort* __restrict__ Z, const ushort* __restrict__ WtS,
    const float* __restrict__ b1, const float* __restrict__ W2,
    float2* __restrict__ beta)
{
  __shared__ ushort As[128][64];
  __shared__ ushort Bs[128][64];
  __shared__ float wsum[128][2];
  const int t = threadIdx.x;
  const int wid = t >> 6, lane = t & 63;
  const int K = SEM;

  const int nwg  = gridDim.x;
  const int orig = blockIdx.x;
  const int q = nwg >> 3, r = nwg & 7;
  const int xcd = orig & 7, idx = orig >> 3;
  const int swz = (xcd < r ? xcd * (q + 1) : r * (q + 1) + (xcd - r) * q) + idx;

  const int bm = swz * 128;
  const int lr = lane & 15, kg = lane >> 4;
  const int sw8 = lr & 7;
  const int mbase = (wid >> 1) * 64, nbase = (wid & 1) * 64;
  const int grow = lane >> 3;
  const int gcol = (((lane & 7) ^ grow)) * 8;

  f32x4 acc[4][4] = {};

  for (int k0 = 0; k0 < K; k0 += 64) {
#pragma unroll
    for (int c = 0; c < 4; ++c) {
      int ch = wid * 4 + c;
      GLOAD_LDS16(Z   + (size_t)(bm + ch * 8 + grow) * K + k0 + gcol, &As[ch * 8][0]);
      GLOAD_LDS16(WtS + (size_t)(ch * 8 + grow) * K + k0 + gcol, &Bs[ch * 8][0]);
    }
    asm volatile("s_waitcnt vmcnt(0)" ::: "memory");
    __syncthreads();
#pragma unroll
    for (int kb = 0; kb < 2; ++kb) {
      const int csw = ((kb * 4 + kg) ^ sw8) * 8;
      bf16x8 av[4], bv[4];
#pragma unroll
      for (int m = 0; m < 4; ++m)
        av[m] = *(const bf16x8*)&As[mbase + m * 16 + lr][csw];
#pragma unroll
      for (int n = 0; n < 4; ++n)
        bv[n] = *(const bf16x8*)&Bs[nbase + n * 16 + lr][csw];
#pragma unroll
      for (int m = 0; m < 4; ++m)
#pragma unroll
        for (int n = 0; n < 4; ++n)
          acc[m][n] = __builtin_amdgcn_mfma_f32_16x16x32_bf16(av[m], bv[n], acc[m][n], 0, 0, 0);
    }
    __syncthreads();
  }

  // epilogue: per-row partial of sum(tanh(T+b1)*W2) over this wave's 64 cols
  float part[4][4];
#pragma unroll
  for (int m = 0; m < 4; ++m)
#pragma unroll
    for (int j = 0; j < 4; ++j) {
      float s = 0.f;
#pragma unroll
      for (int n = 0; n < 4; ++n) {
        int col = nbase + n * 16 + lr;
        float tv = acc[m][n][j] + b1[col];
        tv = fminf(fmaxf(tv, -20.f), 20.f);        // NaN/Inf-safe clamp
        float e = fexp2(2.f * LOG2E * tv);
        s += ((e - 1.f) / (e + 1.f)) * W2[col];
      }
      part[m][j] = s;
    }
  // reduce across the 16 col-lanes (lr bits of lane index)
#pragma unroll
  for (int off = 1; off < 16; off <<= 1)
#pragma unroll
    for (int m = 0; m < 4; ++m)
#pragma unroll
      for (int j = 0; j < 4; ++j)
        part[m][j] += __shfl_xor(part[m][j], off);
  if (lr == 0) {
#pragma unroll
    for (int m = 0; m < 4; ++m)
#pragma unroll
      for (int j = 0; j < 4; ++j)
        wsum[mbase + m * 16 + kg * 4 + j][wid & 1] = part[m][j];
  }
  __syncthreads();
  if (t < 64) {
    float w0 = wsum[2 * t][0] + wsum[2 * t][1];
    float w1 = wsum[2 * t + 1][0] + wsum[2 * t + 1][1];
    float mx = fmaxf(w0, w1);
    float e0 = fexp2((w0 - mx) * LOG2E), e1 = fexp2((w1 - mx) * LOG2E);
    float s = e0 + e1;
    beta[swz * 64 + t] = make_float2(e0 / s, e1 / s);
  }
}

// ------------- fused combine + out GEMM: 128x256 tile, single N pass -------
// A synthesized as beta.x*Z[2*row] + beta.y*Z[2*row+1] (interleaved layout).
__global__ __launch_bounds__(256) void gemm_out(
    const ushort* __restrict__ Z, const ushort* __restrict__ WtO,
    float* __restrict__ out, const float* __restrict__ out_b,
    const float2* __restrict__ beta)
{
  __shared__ ushort As[128][64];   // 16 KB
  __shared__ ushort Bs[256][64];   // 32 KB
  const int t = threadIdx.x;
  const int wid = t >> 6, lane = t & 63;
  const int K = SEM;

  const int nwg  = gridDim.x;
  const int orig = blockIdx.x;
  const int q = nwg >> 3, r = nwg & 7;
  const int xcd = orig & 7, idx = orig >> 3;
  const int swz = (xcd < r ? xcd * (q + 1) : r * (q + 1) + (xcd - r) * q) + idx;

  const int bm = swz * 128;
  const int lr = lane & 15, kg = lane >> 4;
  const int sw8 = lr & 7;
  const int mbase = (wid >> 1) * 64, nbase = (wid & 1) * 128;
  const int grow = lane >> 3;
  const int gcol = (((lane & 7) ^ grow)) * 8;
  const int wcol = (((lane & 7) ^ grow)) * 8;   // swizzled ds_write slot

  f32x4 acc[4][8] = {};

  for (int k0 = 0; k0 < K; k0 += 64) {
#pragma unroll
    for (int c = 0; c < 8; ++c) {
      int ch = wid * 8 + c;            // 0..31
      GLOAD_LDS16(WtO + (size_t)(ch * 8 + grow) * K + k0 + gcol, &Bs[ch * 8][0]);
    }
#pragma unroll
    for (int c = 0; c < 4; ++c) {
      int ch = wid * 4 + c;
      int rl = ch * 8 + grow;          // 0..127 ; rl&7 == grow
      int row = bm + rl;
      const ushort* z0p = Z + (size_t)(2 * row) * SEM + k0 + (lane & 7) * 8;
      const ushort* z1p = z0p + SEM;
      float2 bb = beta[row];
      uint4 a0 = *(const uint4*)z0p;
      uint4 a1 = *(const uint4*)z1p;
      uint rpk[4];
#pragma unroll
      for (int qq = 0; qq < 4; ++qq) {
        uint x0 = ((const uint*)&a0)[qq], x1 = ((const uint*)&a1)[qq];
        float lo = bb.x * b2f(x0 & 0xffffu) + bb.y * b2f(x1 & 0xffffu);
        float hi = bb.x * b2f(x0 >> 16)     + bb.y * b2f(x1 >> 16);
        rpk[qq] = (uint)f2b(lo) | ((uint)f2b(hi) << 16);
      }
      *(uint4*)&As[rl][wcol] = make_uint4(rpk[0], rpk[1], rpk[2], rpk[3]);
    }
    asm volatile("s_waitcnt vmcnt(0)" ::: "memory");
    __syncthreads();
#pragma unroll
    for (int kb = 0; kb < 2; ++kb) {
      const int csw = ((kb * 4 + kg) ^ sw8) * 8;
      bf16x8 av[4], bv[8];
#pragma unroll
      for (int m = 0; m < 4; ++m)
        av[m] = *(const bf16x8*)&As[mbase + m * 16 + lr][csw];
#pragma unroll
      for (int n = 0; n < 8; ++n)
        bv[n] = *(const bf16x8*)&Bs[nbase + n * 16 + lr][csw];
#pragma unroll
      for (int m = 0; m < 4; ++m)
#pragma unroll
        for (int n = 0; n < 8; ++n)
          acc[m][n] = __builtin_amdgcn_mfma_f32_16x16x32_bf16(av[m], bv[n], acc[m][n], 0, 0, 0);
    }
    __syncthreads();
  }

#pragma unroll
  for (int m = 0; m < 4; ++m)
#pragma unroll
    for (int j = 0; j < 4; ++j) {
      int row = bm + mbase + m * 16 + kg * 4 + j;
      if (row >= N_USER) continue;
#pragma unroll
      for (int n = 0; n < 8; ++n) {
        int col = nbase + n * 16 + lr;
        out[(size_t)row * OUT_DIM + col] = acc[m][n][j] + out_b[col];
      }
    }
}

// ---------------- mega prep kernel (grid-strided) --------------------------
constexpr int NB_FOLD  = cdiv(IN_DIM * 16, 256);            // 48
constexpr int NB_CASTU = N_USER * IN_DIM / 8 / 256;         // 18750
constexpr int NB_CASTL = N_LLM * IN_DIM / 8 / 256;          // 1875
constexpr int NB_TTW   = (IN_DIM / 64) * (SEM / 64);        // 96 (x2)
constexpr int NB_TTS   = (SEM / 64) * (HID / 64);           // 16
constexpr int NB_TTO   = (SEM / 64) * (OUT_DIM / 64);       // 32
constexpr int NB_E1    = cdiv(2 * NE, 256);                 // 3125
constexpr int PB0 = NB_FOLD;
constexpr int PB1 = PB0 + NB_CASTU;
constexpr int PB2 = PB1 + NB_CASTL;
constexpr int PB3 = PB2 + NB_TTW;
constexpr int PB4 = PB3 + NB_TTW;
constexpr int PB5 = PB4 + NB_TTS;
constexpr int PB6 = PB5 + NB_TTO;
constexpr int PB7 = PB6 + NB_E1;
constexpr int PREP_GRID = 2048;

// LDS-tiled transpose-cast: W fp32 [K][Nw] -> Bt bf16 [Nw][K], 64x64 tile.
__device__ __forceinline__ void tt_body(const float* __restrict__ W,
                                        ushort* __restrict__ Bt,
                                        int K, int Nw, int tile,
                                        float (*lds)[65], int t)
{
  const int tiles_n = Nw >> 6;
  const int tk = tile / tiles_n, tn = tile - tk * tiles_n;
  const int k0 = tk << 6, n0 = tn << 6;
#pragma unroll
  for (int i = 0; i < 16; ++i) {
    int idx = t + i * 256;
    int rr = idx >> 6, cc = idx & 63;
    lds[rr][cc] = W[(size_t)(k0 + rr) * Nw + n0 + cc];
  }
  __syncthreads();
#pragma unroll
  for (int i = 0; i < 4; ++i) {
    int idx = t + i * 256;                 // 0..1023
    int cc = idx >> 4;                     // 0..63 (output row = n0+cc)
    int rq = (idx & 15) * 4;               // 0,4,...,60
    uint lo = (uint)f2b(lds[rq][cc])     | ((uint)f2b(lds[rq + 1][cc]) << 16);
    uint hi = (uint)f2b(lds[rq + 2][cc]) | ((uint)f2b(lds[rq + 3][cc]) << 16);
    *(uint2*)(Bt + (size_t)(n0 + cc) * K + k0 + rq) = make_uint2(lo, hi);
  }
  __syncthreads();
}

__device__ __forceinline__ void cast_body(const float* __restrict__ x,
                                          ushort* __restrict__ xb, int i)
{
  const float4 a = *(const float4*)(x + (size_t)i * 8);
  const float4 c = *(const float4*)(x + (size_t)i * 8 + 4);
  uint4 o;
  o.x = (uint)f2b(a.x) | ((uint)f2b(a.y) << 16);
  o.y = (uint)f2b(a.z) | ((uint)f2b(a.w) << 16);
  o.z = (uint)f2b(c.x) | ((uint)f2b(c.y) << 16);
  o.w = (uint)f2b(c.z) | ((uint)f2b(c.w) << 16);
  *(uint4*)(xb + (size_t)i * 8) = o;
}

__global__ __launch_bounds__(256) void prep_kernel(
    const float* __restrict__ x_user, const float* __restrict__ x_llm,
    ushort* __restrict__ xb_u, ushort* __restrict__ xb_l,
    const float* __restrict__ Wdst0, const float* __restrict__ adst0,
    const float* __restrict__ Wdst1, const float* __restrict__ adst1,
    const float* __restrict__ Wsrc1, const float* __restrict__ asrc1,
    const float* __restrict__ Wsrc0, const float* __restrict__ asrc0,
    ushort* __restrict__ Wt1x, ushort* __restrict__ Wt0x,
    const float* __restrict__ sem_W1, ushort* __restrict__ WtS,
    const float* __restrict__ out_W, ushort* __restrict__ WtO,
    const int* __restrict__ dst0, const int* __restrict__ dst1,
    int* __restrict__ deg, int* __restrict__ rank)
{
  __shared__ float lds[64][65];   // 16.6 KB, used by transpose sections
  const int t = threadIdx.x;
  for (int b = blockIdx.x; b < PB7; b += PREP_GRID) {
    if (b < PB0) {
      int idxg = b * 256 + t;
      if (idxg < IN_DIM * 16) {
        int k = idxg >> 4, hh = idxg & 15;
        const float* W;
        const float* att;
        if (hh < 4)       { W = Wdst0; att = adst0; }
        else if (hh < 8)  { W = Wdst1; att = adst1; }
        else if (hh < 12) { W = Wsrc1; att = asrc1; }
        else              { W = Wsrc0; att = asrc0; }
        int h = hh & 3;
        float s = 0.f;
#pragma unroll 4
        for (int c = 0; c < HID; ++c)
          s += W[(size_t)k * SEM + h * HID + c] * att[h * HID + c];
        if (hh < 12) Wt1x[(size_t)(512 + hh) * IN_DIM + k] = f2b(s);
        else         Wt0x[(size_t)(512 + h) * IN_DIM + k] = f2b(s);
      }
    } else if (b < PB1) {
      cast_body(x_user, xb_u, (b - PB0) * 256 + t);
    } else if (b < PB2) {
      cast_body(x_llm, xb_l, (b - PB1) * 256 + t);
    } else if (b < PB3) {
      tt_body(Wsrc0, Wt0x, IN_DIM, SEM, b - PB2, lds, t);
    } else if (b < PB4) {
      tt_body(Wsrc1, Wt1x, IN_DIM, SEM, b - PB3, lds, t);
    } else if (b < PB5) {
      tt_body(sem_W1, WtS, SEM, HID, b - PB4, lds, t);
    } else if (b < PB6) {
      tt_body(out_W, WtO, SEM, OUT_DIM, b - PB5, lds, t);
    } else {
      int e = (b - PB6) * 256 + t;
      if (e < 2 * NE) {
        int d = (e < NE) ? dst0[e] : (dst1[e - NE] + N_USER);
        rank[e] = atomicAdd(&deg[d], 1);
      }
    }
  }
}

// -------- scatter src (ushort) into CSR slots — atomic-free, grid-strided --
__global__ void scatter_kernel(const int* __restrict__ src0, const int* __restrict__ dst0,
                               const int* __restrict__ src1, const int* __restrict__ dst1,
                               const int* __restrict__ rp, const int* __restrict__ rank,
                               ushort* __restrict__ scsr)
{
  for (int e = blockIdx.x * 256 + threadIdx.x; e < 2 * NE; e += gridDim.x * 256) {
    bool p1 = (e >= NE);
    int ee = p1 ? e - NE : e;
    int s = p1 ? src1[ee] : src0[ee];
    int d = p1 ? (dst1[ee] + N_USER) : dst0[ee];
    scsr[rp[d] + rank[e]] = (ushort)s;
  }
}

// -------- 3-phase scan over deg[0..n) --------------------------------------
__global__ __launch_bounds__(256) void scan1(const int* __restrict__ deg,
                                             int* __restrict__ bsum, int n)
{
  __shared__ int sm[256];
  int b = blockIdx.x, t = threadIdx.x;
  int base = b * 1024 + t * 4;
  int s = 0;
#pragma unroll
  for (int i = 0; i < 4; ++i) if (base + i < n) s += deg[base + i];
  sm[t] = s;
  __syncthreads();
  for (int off = 128; off > 0; off >>= 1) {
    if (t < off) sm[t] += sm[t + off];
    __syncthreads();
  }
  if (t == 0) bsum[b] = sm[0];
}

__global__ __launch_bounds__(128) void scan2(const int* __restrict__ bsum,
                                             int* __restrict__ boff, int nb,
                                             int* __restrict__ rp_tail, int tailval)
{
  __shared__ int sm[128];
  int t = threadIdx.x;
  int v = (t < nb) ? bsum[t] : 0;
  sm[t] = v;
  __syncthreads();
  for (int off = 1; off < 128; off <<= 1) {
    int x = (t >= off) ? sm[t - off] : 0;
    __syncthreads();
    sm[t] += x;
    __syncthreads();
  }
  if (t < nb) boff[t] = sm[t] - v;
  if (t == 0) *rp_tail = tailval;
}

__global__ __launch_bounds__(256) void scan3(const int* __restrict__ deg,
                                             const int* __restrict__ boff,
                                             int* __restrict__ rp, int n)
{
  __shared__ int sm[256];
  int b = blockIdx.x, t = threadIdx.x;
  int base = b * 1024 + t * 4;
  int v[4];
#pragma unroll
  for (int i = 0; i < 4; ++i) v[i] = (base + i < n) ? deg[base + i] : 0;
  int tsum = v[0] + v[1] + v[2] + v[3];
  sm[t] = tsum;
  __syncthreads();
  for (int off = 1; off < 256; off <<= 1) {
    int x = (t >= off) ? sm[t - off] : 0;
    __syncthreads();
    sm[t] += x;
    __syncthreads();
  }
  int run = sm[t] - tsum + boff[b];
#pragma unroll
  for (int i = 0; i < 4; ++i) {
    if (base + i < n) rp[base + i] = run;
    run += v[i];
  }
}

// -------- unified aggregation: ONE WAVE per dst node -----------------------
// Writes Z in interleaved layout: row = 2*nd + path.
__global__ __launch_bounds__(64) void agg_kernel(
    const ushort* __restrict__ hs0, const ushort* __restrict__ hs1,
    const ushort* __restrict__ srcs,
    const float* __restrict__ logitL, const float* __restrict__ logitU,
    const int* __restrict__ rp,
    const float* __restrict__ bias0, const float* __restrict__ bias1,
    ushort* __restrict__ Zout)
{
  __shared__ ushort s_src[64];
  __shared__ float  s_ev[64][4];
  int node = blockIdx.x, lane = threadIdx.x;
  bool p1 = (node >= N_USER);
  const ushort* hs   = p1 ? hs1 : hs0;
  const float*  bias = p1 ? bias1 : bias0;
  int nd = p1 ? node - N_USER : node;
  float4 ad4 = *(const float4*)(logitU + (size_t)nd * 16 + (p1 ? 4 : 0));
  ad4.x *= LOG2E; ad4.y *= LOG2E; ad4.z *= LOG2E; ad4.w *= LOG2E;
  const float* asbase = p1 ? (logitU + 8) : logitL;
  int h  = lane >> 4;
  int cb = lane * 8;
  float acc[8] = {};
  float dsum = 0.f;
  int jb = rp[node], je = rp[node + 1];
  for (int j0 = jb; j0 < je; j0 += 64) {
    int n = min(64, je - j0);
    __syncthreads();
    if (lane < n) {
      int s = srcs[j0 + lane];
      s_src[lane] = (ushort)s;
      float4 as4 = *(const float4*)(asbase + (size_t)s * 16);
      float v0 = as4.x * LOG2E + ad4.x, v1 = as4.y * LOG2E + ad4.y;
      float v2 = as4.z * LOG2E + ad4.z, v3 = as4.w * LOG2E + ad4.w;
      v0 = (v0 > 0.f) ? v0 : 0.2f * v0;
      v1 = (v1 > 0.f) ? v1 : 0.2f * v1;
      v2 = (v2 > 0.f) ? v2 : 0.2f * v2;
      v3 = (v3 > 0.f) ? v3 : 0.2f * v3;
      s_ev[lane][0] = fexp2(v0);
      s_ev[lane][1] = fexp2(v1);
      s_ev[lane][2] = fexp2(v2);
      s_ev[lane][3] = fexp2(v3);
    }
    __syncthreads();
#pragma unroll 4
    for (int j = 0; j < n; ++j) {
      int s = __builtin_amdgcn_readfirstlane((int)s_src[j]);
      float e = s_ev[j][h];
      const uint4 pv = *(const uint4*)(hs + ((size_t)s << 9) + cb);
      acc[0] += b2f(pv.x & 0xffffu) * e;  acc[1] += b2f(pv.x >> 16) * e;
      acc[2] += b2f(pv.y & 0xffffu) * e;  acc[3] += b2f(pv.y >> 16) * e;
      acc[4] += b2f(pv.z & 0xffffu) * e;  acc[5] += b2f(pv.z >> 16) * e;
      acc[6] += b2f(pv.w & 0xffffu) * e;  acc[7] += b2f(pv.w >> 16) * e;
      dsum += e;
    }
  }
  float inv = 1.f / (dsum + 1e-16f);
  float4 b4a = *(const float4*)(bias + cb);
  float4 b4b = *(const float4*)(bias + cb + 4);
  float bb[8] = { b4a.x, b4a.y, b4a.z, b4a.w, b4b.x, b4b.y, b4b.z, b4b.w };
  uint4 o;
  uint* op = (uint*)&o;
#pragma unroll
  for (int i = 0; i < 4; ++i) {
    float z0 = acc[2 * i]     * inv + bb[2 * i];
    float z1 = acc[2 * i + 1] * inv + bb[2 * i + 1];
    z0 = (z0 > 0.f) ? z0 : fexp2(z0 * LOG2E) - 1.f;
    z1 = (z1 > 0.f) ? z1 : fexp2(z1 * LOG2E) - 1.f;
    op[i] = (uint)f2b(z0) | ((uint)f2b(z1) << 16);
  }
  int zrow = 2 * nd + (p1 ? 1 : 0);
  *(uint4*)(Zout + (size_t)zrow * SEM + cb) = o;
}

extern "C" void kernel_launch(void* const* d_in, const int* in_sizes, int n_in,
                              void* d_out, int out_size, void* d_ws, size_t ws_size,
                              hipStream_t stream)
{
  const float* x_user = (const float*)d_in[0];
  const float* x_llm  = (const float*)d_in[1];
  const int* src0 = (const int*)d_in[2];
  const int* dst0 = (const int*)d_in[3];
  const int* src1 = (const int*)d_in[4];
  const int* dst1 = (const int*)d_in[5];
  const float* Wsrc0 = (const float*)d_in[6];
  const float* Wdst0 = (const float*)d_in[7];
  const float* asrc0 = (const float*)d_in[8];
  const float* adst0 = (const float*)d_in[9];
  const float* bias0 = (const float*)d_in[10];
  const float* Wsrc1 = (const float*)d_in[11];
  const float* Wdst1 = (const float*)d_in[12];
  const float* asrc1 = (const float*)d_in[13];
  const float* adst1 = (const float*)d_in[14];
  const float* bias1 = (const float*)d_in[15];
  const float* sem_W1 = (const float*)d_in[16];
  const float* sem_b1 = (const float*)d_in[17];
  const float* sem_W2 = (const float*)d_in[18];
  const float* out_W  = (const float*)d_in[19];
  const float* out_b  = (const float*)d_in[20];

  char* ws = (char*)d_ws;
  size_t off = 0;
  auto alloc = [&](size_t bytes) -> size_t {
    size_t o = off;
    off += (bytes + 255) & ~(size_t)255;
    return o;
  };

  size_t xbu_off  = alloc((size_t)MP_USER * IN_DIM * 2);
  size_t xbl_off  = alloc((size_t)MP_LLM  * IN_DIM * 2);
  size_t wt0_off  = alloc((size_t)640 * IN_DIM * 2);
  size_t wt1_off  = alloc((size_t)640 * IN_DIM * 2);
  size_t wts_off  = alloc((size_t)HID * SEM * 2);
  size_t wto_off  = alloc((size_t)OUT_DIM * SEM * 2);
  size_t hs0_off  = alloc((size_t)MP_LLM  * SEM * 2);
  size_t hs1_off  = alloc((size_t)MP_USER * SEM * 2);
  size_t Z_off    = alloc((size_t)MP_2U   * SEM * 2);
  size_t sc_off   = alloc((size_t)2 * NE * 2);
  size_t rank_off = alloc((size_t)2 * NE * 4);
  size_t lgu_off  = alloc((size_t)MP_USER * 16 * 4);
  size_t lgl_off  = alloc((size_t)MP_LLM  * 16 * 4);
  size_t beta_off = alloc((size_t)MP_USER * 8);
  size_t deg_off  = alloc((size_t)2 * N_USER * 4);         // zeroed
  size_t zero_end = off;
  size_t rp_off   = alloc((size_t)(2 * N_USER + 1) * 4);
  size_t bs_off   = alloc((size_t)128 * 4);
  size_t bo_off   = alloc((size_t)128 * 4);

  ushort* xb_u  = (ushort*)(ws + xbu_off);
  ushort* xb_l  = (ushort*)(ws + xbl_off);
  ushort* Wt0x  = (ushort*)(ws + wt0_off);
  ushort* Wt1x  = (ushort*)(ws + wt1_off);
  ushort* WtS   = (ushort*)(ws + wts_off);
  ushort* WtO   = (ushort*)(ws + wto_off);
  ushort* hs0b  = (ushort*)(ws + hs0_off);
  ushort* hs1b  = (ushort*)(ws + hs1_off);
  ushort* Zsw   = (ushort*)(ws + Z_off);
  ushort* scsr  = (ushort*)(ws + sc_off);
  int*    rank  = (int*)(ws + rank_off);
  float*  logU  = (float*)(ws + lgu_off);
  float*  logL  = (float*)(ws + lgl_off);
  float2* beta  = (float2*)(ws + beta_off);
  int*    deg   = (int*)(ws + deg_off);
  int*    rp    = (int*)(ws + rp_off);
  int*    bsum  = (int*)(ws + bs_off);
  int*    boff  = (int*)(ws + bo_off);

  hipMemsetAsync(ws + deg_off, 0, zero_end - deg_off, stream);
  hipMemsetAsync(Wt0x + (size_t)512 * IN_DIM, 0, (size_t)128 * IN_DIM * 2, stream);
  hipMemsetAsync(Wt1x + (size_t)512 * IN_DIM, 0, (size_t)128 * IN_DIM * 2, stream);

  // mega prep (grid-strided): fold + casts + tiled transposes + degree/rank
  prep_kernel<<<PREP_GRID, 256, 0, stream>>>(
      x_user, x_llm, xb_u, xb_l,
      Wdst0, adst0, Wdst1, adst1, Wsrc1, asrc1, Wsrc0, asrc0,
      Wt1x, Wt0x, sem_W1, WtS, out_W, WtO,
      dst0, dst1, deg, rank);

  // CSR build over unified node space
  const int NTOT = 2 * N_USER;
  const int NB = cdiv(NTOT, 1024);   // 98
  scan1<<<NB, 256, 0, stream>>>(deg, bsum, NTOT);
  scan2<<<1, 128, 0, stream>>>(bsum, boff, NB, rp + NTOT, 2 * NE);
  scan3<<<NB, 256, 0, stream>>>(deg, boff, rp, NTOT);
  scatter_kernel<<<2048, 256, 0, stream>>>(src0, dst0, src1, dst1, rp, rank, scsr);

  // merged hs GEMMs (5 col-tiles: 4x128 hs + 1 logit)
  {
    dim3 g(640 / 128, GY_USER + GY_LLM);
    gemm_hs<<<g, 256, 0, stream>>>(xb_u, xb_l, Wt1x, Wt0x, hs1b, hs0b, logU, logL);
  }

  // unified aggregation (one wave per node) -> bf16 Z (interleaved rows)
  agg_kernel<<<NTOT, 64, 0, stream>>>(hs0b, hs1b, scsr, logL, logU, rp,
                                      bias0, bias1, Zsw);

  // fused T-GEMM + tanh/W2-reduce + softmax -> beta (T never materialized)
  gemm_beta<<<MP_2U / 128, 256, 0, stream>>>(Zsw, WtS, sem_b1, sem_W2, beta);

  // out = (beta0*Z[2r] + beta1*Z[2r+1]) @ out_W + out_b, single 128x256 pass
  gemm_out<<<GY_USER, 256, 0, stream>>>(Zsw, WtO, (float*)d_out, out_b, beta);
}

// Round 17
// 372.919 us; speedup vs baseline: 1.1117x; 1.0167x over previous
//
#include <hip/hip_runtime.h>
#include <hip/hip_bf16.h>
#include <math.h>

constexpr int IN_DIM  = 768;
constexpr int HID     = 128;
constexpr int OUT_DIM = 256;
constexpr int SEM     = 512;     // HID*HEADS
constexpr int N_USER  = 50000;
constexpr int N_LLM   = 5000;
constexpr int NE      = 400000;

constexpr int MP_USER = 50048;   // 391*128
constexpr int MP_LLM  = 5120;    // 40*128
constexpr int MP_2U   = 100096;  // 782*128
constexpr int GY_USER = MP_USER / 128;   // 391
constexpr int GY_LLM  = MP_LLM / 128;    // 40

typedef unsigned int uint;
typedef unsigned short ushort;
typedef __attribute__((ext_vector_type(8))) short bf16x8;
typedef __attribute__((ext_vector_type(4))) float f32x4;

constexpr int cdiv(int a, int b) { return (a + b - 1) / b; }

__device__ __forceinline__ ushort f2b(float f) {
  uint u = __float_as_uint(f);
  u += 0x7FFFu + ((u >> 16) & 1u);       // RNE
  return (ushort)(u >> 16);
}
__device__ __forceinline__ float b2f(uint bits16) {
  return __uint_as_float(bits16 << 16);
}

__device__ __forceinline__ float fexp2(float x) { return __builtin_amdgcn_exp2f(x); }
#define LOG2E 1.4426950408889634f

#define GLOAD_LDS16(g, l) __builtin_amdgcn_global_load_lds( \
    (const __attribute__((address_space(1))) void*)(g), \
    (__attribute__((address_space(3))) void*)(l), 16, 0, 0)

// LDS XOR swizzle (T2, rule #21): linear LDS dest (gload_lds), pre-permuted
// GLOBAL source slot; reads XOR slot with (row&7). 16-way conflict -> 2-way.
// Z layout: interleaved — row (2*node + path).

// ------------- merged hs GEMM (user+llm, fused logits) + CSR scatter -------
// 1-D grid: blocks [0, NWG_HS) = GEMM tiles (XCD-swizzled over the subrange);
// blocks [NWG_HS, NWG_HS+NB_SC) = atomic-free CSR scatter (independent work
// overlapped into the same dispatch — single stream can't overlap launches).
constexpr int GX_HS  = 5;                       // col tiles: 4x128 hs + 1 logit
constexpr int NWG_HS = GX_HS * (GY_USER + GY_LLM);   // 2155
constexpr int NB_SC  = cdiv(2 * NE, 256);            // 3125
__global__ __launch_bounds__(256) void gemm_hs_sc(
    const ushort* __restrict__ A_u, const ushort* __restrict__ A_l,
    const ushort* __restrict__ Bt_u, const ushort* __restrict__ Bt_l,
    ushort* __restrict__ hs_u, ushort* __restrict__ hs_l,
    float* __restrict__ logU, float* __restrict__ logL,
    const int* __restrict__ src0, const int* __restrict__ dst0,
    const int* __restrict__ src1, const int* __restrict__ dst1,
    const int* __restrict__ rp, const int* __restrict__ rank,
    ushort* __restrict__ scsr)
{
  const int t = threadIdx.x;
  if (blockIdx.x >= NWG_HS) {
    // ---- scatter role: src (ushort) into CSR slot rp[d]+rank[e]
    int e = (blockIdx.x - NWG_HS) * 256 + t;
    if (e < 2 * NE) {
      bool p1 = (e >= NE);
      int ee = p1 ? e - NE : e;
      int s = p1 ? src1[ee] : src0[ee];
      int d = p1 ? (dst1[ee] + N_USER) : dst0[ee];
      scsr[rp[d] + rank[e]] = (ushort)s;
    }
    return;
  }

  __shared__ ushort As[128][64];
  __shared__ ushort Bs[128][64];
  const int wid = t >> 6, lane = t & 63;
  const int K = IN_DIM;

  // bijective XCD swizzle over the GEMM subrange only
  const int nwg  = NWG_HS;
  const int orig = blockIdx.x;
  const int q = nwg >> 3, r = nwg & 7;
  const int xcd = orig & 7, idx = orig >> 3;
  const int swz = (xcd < r ? xcd * (q + 1) : r * (q + 1) + (xcd - r) * q) + idx;
  const int bxi = swz % GX_HS, byi0 = swz / GX_HS;

  const bool llm = (byi0 >= GY_USER);
  const int byi = llm ? byi0 - GY_USER : byi0;
  const ushort* A    = llm ? A_l : A_u;
  const ushort* Bt   = llm ? Bt_l : Bt_u;
  ushort* hs         = llm ? hs_l : hs_u;
  float* logit       = llm ? logL : logU;

  const int bm = byi * 128, bn = bxi * 128;
  const int lr = lane & 15, kg = lane >> 4;
  const int sw8 = lr & 7;
  const int mbase = (wid >> 1) * 64, nbase = (wid & 1) * 64;
  const int grow = lane >> 3;
  const int gcol = (((lane & 7) ^ grow)) * 8;

  f32x4 acc[4][4] = {};

  for (int k0 = 0; k0 < K; k0 += 64) {
#pragma unroll
    for (int c = 0; c < 4; ++c) {
      int ch = wid * 4 + c;
      GLOAD_LDS16(A  + (size_t)(bm + ch * 8 + grow) * K + k0 + gcol, &As[ch * 8][0]);
      GLOAD_LDS16(Bt + (size_t)(bn + ch * 8 + grow) * K + k0 + gcol, &Bs[ch * 8][0]);
    }
    asm volatile("s_waitcnt vmcnt(0)" ::: "memory");
    __syncthreads();
#pragma unroll
    for (int kb = 0; kb < 2; ++kb) {
      const int csw = ((kb * 4 + kg) ^ sw8) * 8;
      bf16x8 av[4], bv[4];
#pragma unroll
      for (int m = 0; m < 4; ++m)
        av[m] = *(const bf16x8*)&As[mbase + m * 16 + lr][csw];
#pragma unroll
      for (int n = 0; n < 4; ++n)
        bv[n] = *(const bf16x8*)&Bs[nbase + n * 16 + lr][csw];
#pragma unroll
      for (int m = 0; m < 4; ++m)
#pragma unroll
        for (int n = 0; n < 4; ++n)
          acc[m][n] = __builtin_amdgcn_mfma_f32_16x16x32_bf16(av[m], bv[n], acc[m][n], 0, 0, 0);
    }
    __syncthreads();
  }

  if (bxi == GX_HS - 1) {
    if (nbase == 0) {
#pragma unroll
      for (int m = 0; m < 4; ++m)
#pragma unroll
        for (int j = 0; j < 4; ++j) {
          int row = bm + mbase + m * 16 + kg * 4 + j;
          logit[(size_t)row * 16 + lr] = acc[m][0][j];
        }
    }
    return;
  }

#pragma unroll
  for (int m = 0; m < 4; ++m)
#pragma unroll
    for (int j = 0; j < 4; ++j) {
      int row = bm + mbase + m * 16 + kg * 4 + j;
#pragma unroll
      for (int n = 0; n < 4; ++n) {
        int col = bn + nbase + n * 16 + lr;
        hs[(size_t)row * SEM + col] = f2b(acc[m][n][j]);
      }
    }
}

// ------------- fused T-GEMM + semantic softmax -> beta ---------------------
__global__ __launch_bounds__(256) void gemm_beta(
    const ushort* __restrict__ Z, const ushort* __restrict__ WtS,
    const float* __restrict__ b1, const float* __restrict__ W2,
    float2* __restrict__ beta)
{
  __shared__ ushort As[128][64];
  __shared__ ushort Bs[128][64];
  __shared__ float wsum[128][2];
  const int t = threadIdx.x;
  const int wid = t >> 6, lane = t & 63;
  const int K = SEM;

  const int nwg  = gridDim.x;
  const int orig = blockIdx.x;
  const int q = nwg >> 3, r = nwg & 7;
  const int xcd = orig & 7, idx = orig >> 3;
  const int swz = (xcd < r ? xcd * (q + 1) : r * (q + 1) + (xcd - r) * q) + idx;

  const int bm = swz * 128;
  const int lr = lane & 15, kg = lane >> 4;
  const int sw8 = lr & 7;
  const int mbase = (wid >> 1) * 64, nbase = (wid & 1) * 64;
  const int grow = lane >> 3;
  const int gcol = (((lane & 7) ^ grow)) * 8;

  f32x4 acc[4][4] = {};

  for (int k0 = 0; k0 < K; k0 += 64) {
#pragma unroll
    for (int c = 0; c < 4; ++c) {
      int ch = wid * 4 + c;
      GLOAD_LDS16(Z   + (size_t)(bm + ch * 8 + grow) * K + k0 + gcol, &As[ch * 8][0]);
      GLOAD_LDS16(WtS + (size_t)(ch * 8 + grow) * K + k0 + gcol, &Bs[ch * 8][0]);
    }
    asm volatile("s_waitcnt vmcnt(0)" ::: "memory");
    __syncthreads();
#pragma unroll
    for (int kb = 0; kb < 2; ++kb) {
      const int csw = ((kb * 4 + kg) ^ sw8) * 8;
      bf16x8 av[4], bv[4];
#pragma unroll
      for (int m = 0; m < 4; ++m)
        av[m] = *(const bf16x8*)&As[mbase + m * 16 + lr][csw];
#pragma unroll
      for (int n = 0; n < 4; ++n)
        bv[n] = *(const bf16x8*)&Bs[nbase + n * 16 + lr][csw];
#pragma unroll
      for (int m = 0; m < 4; ++m)
#pragma unroll
        for (int n = 0; n < 4; ++n)
          acc[m][n] = __builtin_amdgcn_mfma_f32_16x16x32_bf16(av[m], bv[n], acc[m][n], 0, 0, 0);
    }
    __syncthreads();
  }

  float part[4][4];
#pragma unroll
  for (int m = 0; m < 4; ++m)
#pragma unroll
    for (int j = 0; j < 4; ++j) {
      float s = 0.f;
#pragma unroll
      for (int n = 0; n < 4; ++n) {
        int col = nbase + n * 16 + lr;
        float tv = acc[m][n][j] + b1[col];
        tv = fminf(fmaxf(tv, -20.f), 20.f);        // NaN/Inf-safe clamp
        float e = fexp2(2.f * LOG2E * tv);
        s += ((e - 1.f) / (e + 1.f)) * W2[col];
      }
      part[m][j] = s;
    }
#pragma unroll
  for (int off = 1; off < 16; off <<= 1)
#pragma unroll
    for (int m = 0; m < 4; ++m)
#pragma unroll
      for (int j = 0; j < 4; ++j)
        part[m][j] += __shfl_xor(part[m][j], off);
  if (lr == 0) {
#pragma unroll
    for (int m = 0; m < 4; ++m)
#pragma unroll
      for (int j = 0; j < 4; ++j)
        wsum[mbase + m * 16 + kg * 4 + j][wid & 1] = part[m][j];
  }
  __syncthreads();
  if (t < 64) {
    float w0 = wsum[2 * t][0] + wsum[2 * t][1];
    float w1 = wsum[2 * t + 1][0] + wsum[2 * t + 1][1];
    float mx = fmaxf(w0, w1);
    float e0 = fexp2((w0 - mx) * LOG2E), e1 = fexp2((w1 - mx) * LOG2E);
    float s = e0 + e1;
    beta[swz * 64 + t] = make_float2(e0 / s, e1 / s);
  }
}

// ------------- fused combine + out GEMM: 128x256 tile, single N pass -------
__global__ __launch_bounds__(256) void gemm_out(
    const ushort* __restrict__ Z, const ushort* __restrict__ WtO,
    float* __restrict__ out, const float* __restrict__ out_b,
    const float2* __restrict__ beta)
{
  __shared__ ushort As[128][64];   // 16 KB
  __shared__ ushort Bs[256][64];   // 32 KB
  const int t = threadIdx.x;
  const int wid = t >> 6, lane = t & 63;
  const int K = SEM;

  const int nwg  = gridDim.x;
  const int orig = blockIdx.x;
  const int q = nwg >> 3, r = nwg & 7;
  const int xcd = orig & 7, idx = orig >> 3;
  const int swz = (xcd < r ? xcd * (q + 1) : r * (q + 1) + (xcd - r) * q) + idx;

  const int bm = swz * 128;
  const int lr = lane & 15, kg = lane >> 4;
  const int sw8 = lr & 7;
  const int mbase = (wid >> 1) * 64, nbase = (wid & 1) * 128;
  const int grow = lane >> 3;
  const int gcol = (((lane & 7) ^ grow)) * 8;
  const int wcol = (((lane & 7) ^ grow)) * 8;   // swizzled ds_write slot

  f32x4 acc[4][8] = {};

  for (int k0 = 0; k0 < K; k0 += 64) {
#pragma unroll
    for (int c = 0; c < 8; ++c) {
      int ch = wid * 8 + c;            // 0..31
      GLOAD_LDS16(WtO + (size_t)(ch * 8 + grow) * K + k0 + gcol, &Bs[ch * 8][0]);
    }
#pragma unroll
    for (int c = 0; c < 4; ++c) {
      int ch = wid * 4 + c;
      int rl = ch * 8 + grow;          // 0..127 ; rl&7 == grow
      int row = bm + rl;
      const ushort* z0p = Z + (size_t)(2 * row) * SEM + k0 + (lane & 7) * 8;
      const ushort* z1p = z0p + SEM;
      float2 bb = beta[row];
      uint4 a0 = *(const uint4*)z0p;
      uint4 a1 = *(const uint4*)z1p;
      uint rpk[4];
#pragma unroll
      for (int qq = 0; qq < 4; ++qq) {
        uint x0 = ((const uint*)&a0)[qq], x1 = ((const uint*)&a1)[qq];
        float lo = bb.x * b2f(x0 & 0xffffu) + bb.y * b2f(x1 & 0xffffu);
        float hi = bb.x * b2f(x0 >> 16)     + bb.y * b2f(x1 >> 16);
        rpk[qq] = (uint)f2b(lo) | ((uint)f2b(hi) << 16);
      }
      *(uint4*)&As[rl][wcol] = make_uint4(rpk[0], rpk[1], rpk[2], rpk[3]);
    }
    asm volatile("s_waitcnt vmcnt(0)" ::: "memory");
    __syncthreads();
#pragma unroll
    for (int kb = 0; kb < 2; ++kb) {
      const int csw = ((kb * 4 + kg) ^ sw8) * 8;
      bf16x8 av[4], bv[8];
#pragma unroll
      for (int m = 0; m < 4; ++m)
        av[m] = *(const bf16x8*)&As[mbase + m * 16 + lr][csw];
#pragma unroll
      for (int n = 0; n < 8; ++n)
        bv[n] = *(const bf16x8*)&Bs[nbase + n * 16 + lr][csw];
#pragma unroll
      for (int m = 0; m < 4; ++m)
#pragma unroll
        for (int n = 0; n < 8; ++n)
          acc[m][n] = __builtin_amdgcn_mfma_f32_16x16x32_bf16(av[m], bv[n], acc[m][n], 0, 0, 0);
    }
    __syncthreads();
  }

#pragma unroll
  for (int m = 0; m < 4; ++m)
#pragma unroll
    for (int j = 0; j < 4; ++j) {
      int row = bm + mbase + m * 16 + kg * 4 + j;
      if (row >= N_USER) continue;
#pragma unroll
      for (int n = 0; n < 8; ++n) {
        int col = nbase + n * 16 + lr;
        out[(size_t)row * OUT_DIM + col] = acc[m][n][j] + out_b[col];
      }
    }
}

// ---------------- mega prep kernel (grid-strided) --------------------------
constexpr int NB_FOLD  = cdiv(IN_DIM * 16, 256);            // 48
constexpr int NB_CASTU = N_USER * IN_DIM / 8 / 256;         // 18750
constexpr int NB_CASTL = N_LLM * IN_DIM / 8 / 256;          // 1875
constexpr int NB_TTW   = (IN_DIM / 64) * (SEM / 64);        // 96 (x2)
constexpr int NB_TTS   = (SEM / 64) * (HID / 64);           // 16
constexpr int NB_TTO   = (SEM / 64) * (OUT_DIM / 64);       // 32
constexpr int NB_E1    = cdiv(2 * NE, 256);                 // 3125
constexpr int PB0 = NB_FOLD;
constexpr int PB1 = PB0 + NB_CASTU;
constexpr int PB2 = PB1 + NB_CASTL;
constexpr int PB3 = PB2 + NB_TTW;
constexpr int PB4 = PB3 + NB_TTW;
constexpr int PB5 = PB4 + NB_TTS;
constexpr int PB6 = PB5 + NB_TTO;
constexpr int PB7 = PB6 + NB_E1;
constexpr int PREP_GRID = 2048;

// LDS-tiled transpose-cast: W fp32 [K][Nw] -> Bt bf16 [Nw][K], 64x64 tile.
__device__ __forceinline__ void tt_body(const float* __restrict__ W,
                                        ushort* __restrict__ Bt,
                                        int K, int Nw, int tile,
                                        float (*lds)[65], int t)
{
  const int tiles_n = Nw >> 6;
  const int tk = tile / tiles_n, tn = tile - tk * tiles_n;
  const int k0 = tk << 6, n0 = tn << 6;
#pragma unroll
  for (int i = 0; i < 16; ++i) {
    int idx = t + i * 256;
    int rr = idx >> 6, cc = idx & 63;
    lds[rr][cc] = W[(size_t)(k0 + rr) * Nw + n0 + cc];
  }
  __syncthreads();
#pragma unroll
  for (int i = 0; i < 4; ++i) {
    int idx = t + i * 256;                 // 0..1023
    int cc = idx >> 4;                     // 0..63 (output row = n0+cc)
    int rq = (idx & 15) * 4;               // 0,4,...,60
    uint lo = (uint)f2b(lds[rq][cc])     | ((uint)f2b(lds[rq + 1][cc]) << 16);
    uint hi = (uint)f2b(lds[rq + 2][cc]) | ((uint)f2b(lds[rq + 3][cc]) << 16);
    *(uint2*)(Bt + (size_t)(n0 + cc) * K + k0 + rq) = make_uint2(lo, hi);
  }
  __syncthreads();
}

__device__ __forceinline__ void cast_body(const float* __restrict__ x,
                                          ushort* __restrict__ xb, int i)
{
  const float4 a = *(const float4*)(x + (size_t)i * 8);
  const float4 c = *(const float4*)(x + (size_t)i * 8 + 4);
  uint4 o;
  o.x = (uint)f2b(a.x) | ((uint)f2b(a.y) << 16);
  o.y = (uint)f2b(a.z) | ((uint)f2b(a.w) << 16);
  o.z = (uint)f2b(c.x) | ((uint)f2b(c.y) << 16);
  o.w = (uint)f2b(c.z) | ((uint)f2b(c.w) << 16);
  *(uint4*)(xb + (size_t)i * 8) = o;
}

__global__ __launch_bounds__(256) void prep_kernel(
    const float* __restrict__ x_user, const float* __restrict__ x_llm,
    ushort* __restrict__ xb_u, ushort* __restrict__ xb_l,
    const float* __restrict__ Wdst0, const float* __restrict__ adst0,
    const float* __restrict__ Wdst1, const float* __restrict__ adst1,
    const float* __restrict__ Wsrc1, const float* __restrict__ asrc1,
    const float* __restrict__ Wsrc0, const float* __restrict__ asrc0,
    ushort* __restrict__ Wt1x, ushort* __restrict__ Wt0x,
    const float* __restrict__ sem_W1, ushort* __restrict__ WtS,
    const float* __restrict__ out_W, ushort* __restrict__ WtO,
    const int* __restrict__ dst0, const int* __restrict__ dst1,
    int* __restrict__ deg, int* __restrict__ rank)
{
  __shared__ float lds[64][65];   // 16.6 KB, used by transpose sections
  const int t = threadIdx.x;
  for (int b = blockIdx.x; b < PB7; b += PREP_GRID) {
    if (b < PB0) {
      int idxg = b * 256 + t;
      if (idxg < IN_DIM * 16) {
        int k = idxg >> 4, hh = idxg & 15;
        const float* W;
        const float* att;
        if (hh < 4)       { W = Wdst0; att = adst0; }
        else if (hh < 8)  { W = Wdst1; att = adst1; }
        else if (hh < 12) { W = Wsrc1; att = asrc1; }
        else              { W = Wsrc0; att = asrc0; }
        int h = hh & 3;
        float s = 0.f;
#pragma unroll 4
        for (int c = 0; c < HID; ++c)
          s += W[(size_t)k * SEM + h * HID + c] * att[h * HID + c];
        if (hh < 12) Wt1x[(size_t)(512 + hh) * IN_DIM + k] = f2b(s);
        else         Wt0x[(size_t)(512 + h) * IN_DIM + k] = f2b(s);
      }
    } else if (b < PB1) {
      cast_body(x_user, xb_u, (b - PB0) * 256 + t);
    } else if (b < PB2) {
      cast_body(x_llm, xb_l, (b - PB1) * 256 + t);
    } else if (b < PB3) {
      tt_body(Wsrc0, Wt0x, IN_DIM, SEM, b - PB2, lds, t);
    } else if (b < PB4) {
      tt_body(Wsrc1, Wt1x, IN_DIM, SEM, b - PB3, lds, t);
    } else if (b < PB5) {
      tt_body(sem_W1, WtS, SEM, HID, b - PB4, lds, t);
    } else if (b < PB6) {
      tt_body(out_W, WtO, SEM, OUT_DIM, b - PB5, lds, t);
    } else {
      int e = (b - PB6) * 256 + t;
      if (e < 2 * NE) {
        int d = (e < NE) ? dst0[e] : (dst1[e - NE] + N_USER);
        rank[e] = atomicAdd(&deg[d], 1);
      }
    }
  }
}

// -------- 3-phase scan over deg[0..n) --------------------------------------
__global__ __launch_bounds__(256) void scan1(const int* __restrict__ deg,
                                             int* __restrict__ bsum, int n)
{
  __shared__ int sm[256];
  int b = blockIdx.x, t = threadIdx.x;
  int base = b * 1024 + t * 4;
  int s = 0;
#pragma unroll
  for (int i = 0; i < 4; ++i) if (base + i < n) s += deg[base + i];
  sm[t] = s;
  __syncthreads();
  for (int off = 128; off > 0; off >>= 1) {
    if (t < off) sm[t] += sm[t + off];
    __syncthreads();
  }
  if (t == 0) bsum[b] = sm[0];
}

__global__ __launch_bounds__(128) void scan2(const int* __restrict__ bsum,
                                             int* __restrict__ boff, int nb,
                                             int* __restrict__ rp_tail, int tailval)
{
  __shared__ int sm[128];
  int t = threadIdx.x;
  int v = (t < nb) ? bsum[t] : 0;
  sm[t] = v;
  __syncthreads();
  for (int off = 1; off < 128; off <<= 1) {
    int x = (t >= off) ? sm[t - off] : 0;
    __syncthreads();
    sm[t] += x;
    __syncthreads();
  }
  if (t < nb) boff[t] = sm[t] - v;
  if (t == 0) *rp_tail = tailval;
}

__global__ __launch_bounds__(256) void scan3(const int* __restrict__ deg,
                                             const int* __restrict__ boff,
                                             int* __restrict__ rp, int n)
{
  __shared__ int sm[256];
  int b = blockIdx.x, t = threadIdx.x;
  int base = b * 1024 + t * 4;
  int v[4];
#pragma unroll
  for (int i = 0; i < 4; ++i) v[i] = (base + i < n) ? deg[base + i] : 0;
  int tsum = v[0] + v[1] + v[2] + v[3];
  sm[t] = tsum;
  __syncthreads();
  for (int off = 1; off < 256; off <<= 1) {
    int x = (t >= off) ? sm[t - off] : 0;
    __syncthreads();
    sm[t] += x;
    __syncthreads();
  }
  int run = sm[t] - tsum + boff[b];
#pragma unroll
  for (int i = 0; i < 4; ++i) {
    if (base + i < n) rp[base + i] = run;
    run += v[i];
  }
}

// -------- unified aggregation: ONE WAVE per dst node -----------------------
// Writes Z in interleaved layout: row = 2*nd + path.
__global__ __launch_bounds__(64) void agg_kernel(
    const ushort* __restrict__ hs0, const ushort* __restrict__ hs1,
    const ushort* __restrict__ srcs,
    const float* __restrict__ logitL, const float* __restrict__ logitU,
    const int* __restrict__ rp,
    const float* __restrict__ bias0, const float* __restrict__ bias1,
    ushort* __restrict__ Zout)
{
  __shared__ ushort s_src[64];
  __shared__ float  s_ev[64][4];
  int node = blockIdx.x, lane = threadIdx.x;
  bool p1 = (node >= N_USER);
  const ushort* hs   = p1 ? hs1 : hs0;
  const float*  bias = p1 ? bias1 : bias0;
  int nd = p1 ? node - N_USER : node;
  float4 ad4 = *(const float4*)(logitU + (size_t)nd * 16 + (p1 ? 4 : 0));
  ad4.x *= LOG2E; ad4.y *= LOG2E; ad4.z *= LOG2E; ad4.w *= LOG2E;
  const float* asbase = p1 ? (logitU + 8) : logitL;
  int h  = lane >> 4;
  int cb = lane * 8;
  float acc[8] = {};
  float dsum = 0.f;
  int jb = rp[node], je = rp[node + 1];
  for (int j0 = jb; j0 < je; j0 += 64) {
    int n = min(64, je - j0);
    __syncthreads();
    if (lane < n) {
      int s = srcs[j0 + lane];
      s_src[lane] = (ushort)s;
      float4 as4 = *(const float4*)(asbase + (size_t)s * 16);
      float v0 = as4.x * LOG2E + ad4.x, v1 = as4.y * LOG2E + ad4.y;
      float v2 = as4.z * LOG2E + ad4.z, v3 = as4.w * LOG2E + ad4.w;
      v0 = (v0 > 0.f) ? v0 : 0.2f * v0;
      v1 = (v1 > 0.f) ? v1 : 0.2f * v1;
      v2 = (v2 > 0.f) ? v2 : 0.2f * v2;
      v3 = (v3 > 0.f) ? v3 : 0.2f * v3;
      s_ev[lane][0] = fexp2(v0);
      s_ev[lane][1] = fexp2(v1);
      s_ev[lane][2] = fexp2(v2);
      s_ev[lane][3] = fexp2(v3);
    }
    __syncthreads();
#pragma unroll 4
    for (int j = 0; j < n; ++j) {
      int s = __builtin_amdgcn_readfirstlane((int)s_src[j]);
      float e = s_ev[j][h];
      const uint4 pv = *(const uint4*)(hs + ((size_t)s << 9) + cb);
      acc[0] += b2f(pv.x & 0xffffu) * e;  acc[1] += b2f(pv.x >> 16) * e;
      acc[2] += b2f(pv.y & 0xffffu) * e;  acc[3] += b2f(pv.y >> 16) * e;
      acc[4] += b2f(pv.z & 0xffffu) * e;  acc[5] += b2f(pv.z >> 16) * e;
      acc[6] += b2f(pv.w & 0xffffu) * e;  acc[7] += b2f(pv.w >> 16) * e;
      dsum += e;
    }
  }
  float inv = 1.f / (dsum + 1e-16f);
  float4 b4a = *(const float4*)(bias + cb);
  float4 b4b = *(const float4*)(bias + cb + 4);
  float bb[8] = { b4a.x, b4a.y, b4a.z, b4a.w, b4b.x, b4b.y, b4b.z, b4b.w };
  uint4 o;
  uint* op = (uint*)&o;
#pragma unroll
  for (int i = 0; i < 4; ++i) {
    float z0 = acc[2 * i]     * inv + bb[2 * i];
    float z1 = acc[2 * i + 1] * inv + bb[2 * i + 1];
    z0 = (z0 > 0.f) ? z0 : fexp2(z0 * LOG2E) - 1.f;
    z1 = (z1 > 0.f) ? z1 : fexp2(z1 * LOG2E) - 1.f;
    op[i] = (uint)f2b(z0) | ((uint)f2b(z1) << 16);
  }
  int zrow = 2 * nd + (p1 ? 1 : 0);
  *(uint4*)(Zout + (size_t)zrow * SEM + cb) = o;
}

extern "C" void kernel_launch(void* const* d_in, const int* in_sizes, int n_in,
                              void* d_out, int out_size, void* d_ws, size_t ws_size,
                              hipStream_t stream)
{
  const float* x_user = (const float*)d_in[0];
  const float* x_llm  = (const float*)d_in[1];
  const int* src0 = (const int*)d_in[2];
  const int* dst0 = (const int*)d_in[3];
  const int* src1 = (const int*)d_in[4];
  const int* dst1 = (const int*)d_in[5];
  const float* Wsrc0 = (const float*)d_in[6];
  const float* Wdst0 = (const float*)d_in[7];
  const float* asrc0 = (const float*)d_in[8];
  const float* adst0 = (const float*)d_in[9];
  const float* bias0 = (const float*)d_in[10];
  const float* Wsrc1 = (const float*)d_in[11];
  const float* Wdst1 = (const float*)d_in[12];
  const float* asrc1 = (const float*)d_in[13];
  const float* adst1 = (const float*)d_in[14];
  const float* bias1 = (const float*)d_in[15];
  const float* sem_W1 = (const float*)d_in[16];
  const float* sem_b1 = (const float*)d_in[17];
  const float* sem_W2 = (const float*)d_in[18];
  const float* out_W  = (const float*)d_in[19];
  const float* out_b  = (const float*)d_in[20];

  char* ws = (char*)d_ws;
  size_t off = 0;
  auto alloc = [&](size_t bytes) -> size_t {
    size_t o = off;
    off += (bytes + 255) & ~(size_t)255;
    return o;
  };

  size_t xbu_off  = alloc((size_t)MP_USER * IN_DIM * 2);
  size_t xbl_off  = alloc((size_t)MP_LLM  * IN_DIM * 2);
  size_t wt0_off  = alloc((size_t)640 * IN_DIM * 2);
  size_t wt1_off  = alloc((size_t)640 * IN_DIM * 2);
  size_t wts_off  = alloc((size_t)HID * SEM * 2);
  size_t wto_off  = alloc((size_t)OUT_DIM * SEM * 2);
  size_t hs0_off  = alloc((size_t)MP_LLM  * SEM * 2);
  size_t hs1_off  = alloc((size_t)MP_USER * SEM * 2);
  size_t Z_off    = alloc((size_t)MP_2U   * SEM * 2);
  size_t sc_off   = alloc((size_t)2 * NE * 2);
  size_t rank_off = alloc((size_t)2 * NE * 4);
  size_t lgu_off  = alloc((size_t)MP_USER * 16 * 4);
  size_t lgl_off  = alloc((size_t)MP_LLM  * 16 * 4);
  size_t beta_off = alloc((size_t)MP_USER * 8);
  size_t deg_off  = alloc((size_t)2 * N_USER * 4);         // zeroed
  size_t zero_end = off;
  size_t rp_off   = alloc((size_t)(2 * N_USER + 1) * 4);
  size_t bs_off   = alloc((size_t)128 * 4);
  size_t bo_off   = alloc((size_t)128 * 4);

  ushort* xb_u  = (ushort*)(ws + xbu_off);
  ushort* xb_l  = (ushort*)(ws + xbl_off);
  ushort* Wt0x  = (ushort*)(ws + wt0_off);
  ushort* Wt1x  = (ushort*)(ws + wt1_off);
  ushort* WtS   = (ushort*)(ws + wts_off);
  ushort* WtO   = (ushort*)(ws + wto_off);
  ushort* hs0b  = (ushort*)(ws + hs0_off);
  ushort* hs1b  = (ushort*)(ws + hs1_off);
  ushort* Zsw   = (ushort*)(ws + Z_off);
  ushort* scsr  = (ushort*)(ws + sc_off);
  int*    rank  = (int*)(ws + rank_off);
  float*  logU  = (float*)(ws + lgu_off);
  float*  logL  = (float*)(ws + lgl_off);
  float2* beta  = (float2*)(ws + beta_off);
  int*    deg   = (int*)(ws + deg_off);
  int*    rp    = (int*)(ws + rp_off);
  int*    bsum  = (int*)(ws + bs_off);
  int*    boff  = (int*)(ws + bo_off);

  hipMemsetAsync(ws + deg_off, 0, zero_end - deg_off, stream);
  hipMemsetAsync(Wt0x + (size_t)512 * IN_DIM, 0, (size_t)128 * IN_DIM * 2, stream);
  hipMemsetAsync(Wt1x + (size_t)512 * IN_DIM, 0, (size_t)128 * IN_DIM * 2, stream);

  // mega prep (grid-strided): fold + casts + tiled transposes + degree/rank
  prep_kernel<<<PREP_GRID, 256, 0, stream>>>(
      x_user, x_llm, xb_u, xb_l,
      Wdst0, adst0, Wdst1, adst1, Wsrc1, asrc1, Wsrc0, asrc0,
      Wt1x, Wt0x, sem_W1, WtS, out_W, WtO,
      dst0, dst1, deg, rank);

  // CSR row pointers
  const int NTOT = 2 * N_USER;
  const int NB = cdiv(NTOT, 1024);   // 98
  scan1<<<NB, 256, 0, stream>>>(deg, bsum, NTOT);
  scan2<<<1, 128, 0, stream>>>(bsum, boff, NB, rp + NTOT, 2 * NE);
  scan3<<<NB, 256, 0, stream>>>(deg, boff, rp, NTOT);

  // merged hs GEMMs + CSR scatter (independent work in one dispatch)
  gemm_hs_sc<<<NWG_HS + NB_SC, 256, 0, stream>>>(
      xb_u, xb_l, Wt1x, Wt0x, hs1b, hs0b, logU, logL,
      src0, dst0, src1, dst1, rp, rank, scsr);

  // unified aggregation (one wave per node) -> bf16 Z (interleaved rows)
  agg_kernel<<<NTOT, 64, 0, stream>>>(hs0b, hs1b, scsr, logL, logU, rp,
                                      bias0, bias1, Zsw);

  // fused T-GEMM + tanh/W2-reduce + softmax -> beta (T never materialized)
  gemm_beta<<<MP_2U / 128, 256, 0, stream>>>(Zsw, WtS, sem_b1, sem_W2, beta);

  // out = (beta0*Z[2r] + beta1*Z[2r+1]) @ out_W + out_b, single 128x256 pass
  gemm_out<<<GY_USER, 256, 0, stream>>>(Zsw, WtO, (float*)d_out, out_b, beta);
}

// Round 18
// 354.117 us; speedup vs baseline: 1.1708x; 1.0531x over previous
//
#include <hip/hip_runtime.h>
#include <hip/hip_bf16.h>
#include <math.h>

constexpr int IN_DIM  = 768;
constexpr int HID     = 128;
constexpr int OUT_DIM = 256;
constexpr int SEM     = 512;     // HID*HEADS
constexpr int N_USER  = 50000;
constexpr int N_LLM   = 5000;
constexpr int NE      = 400000;

constexpr int MP_USER = 50048;   // 391*128
constexpr int MP_LLM  = 5120;    // 40*128
constexpr int MP_2U   = 100096;  // 782*128
constexpr int GY_USER = MP_USER / 128;   // 391
constexpr int GY_LLM  = MP_LLM / 128;    // 40

typedef unsigned int uint;
typedef unsigned short ushort;
typedef __attribute__((ext_vector_type(8))) short bf16x8;
typedef __attribute__((ext_vector_type(4))) float f32x4;

constexpr int cdiv(int a, int b) { return (a + b - 1) / b; }

__device__ __forceinline__ ushort f2b(float f) {
  uint u = __float_as_uint(f);
  u += 0x7FFFu + ((u >> 16) & 1u);       // RNE
  return (ushort)(u >> 16);
}
__device__ __forceinline__ float b2f(uint bits16) {
  return __uint_as_float(bits16 << 16);
}

__device__ __forceinline__ float fexp2(float x) { return __builtin_amdgcn_exp2f(x); }
#define LOG2E 1.4426950408889634f

#define GLOAD_LDS16(g, l) __builtin_amdgcn_global_load_lds( \
    (const __attribute__((address_space(1))) void*)(g), \
    (__attribute__((address_space(3))) void*)(l), 16, 0, 0)

// LDS XOR swizzle (T2, rule #21): linear LDS dest (gload_lds), pre-permuted
// GLOBAL source slot; reads XOR slot with (row&7). 16-way conflict -> 2-way.
// Z layout: interleaved — row (2*node + path).

// ------------- merged hs GEMM (user+llm, fused logits) + CSR scatter -------
constexpr int GX_HS  = 5;                       // col tiles: 4x128 hs + 1 logit
constexpr int NWG_HS = GX_HS * (GY_USER + GY_LLM);   // 2155
constexpr int NB_SC  = cdiv(2 * NE, 256);            // 3125
__global__ __launch_bounds__(256) void gemm_hs_sc(
    const ushort* __restrict__ A_u, const ushort* __restrict__ A_l,
    const ushort* __restrict__ Bt_u, const ushort* __restrict__ Bt_l,
    ushort* __restrict__ hs_u, ushort* __restrict__ hs_l,
    float* __restrict__ logU, float* __restrict__ logL,
    const int* __restrict__ src0, const int* __restrict__ dst0,
    const int* __restrict__ src1, const int* __restrict__ dst1,
    const int* __restrict__ rp, const int* __restrict__ rank,
    ushort* __restrict__ scsr)
{
  const int t = threadIdx.x;
  if (blockIdx.x >= NWG_HS) {
    int e = (blockIdx.x - NWG_HS) * 256 + t;
    if (e < 2 * NE) {
      bool p1 = (e >= NE);
      int ee = p1 ? e - NE : e;
      int s = p1 ? src1[ee] : src0[ee];
      int d = p1 ? (dst1[ee] + N_USER) : dst0[ee];
      scsr[rp[d] + rank[e]] = (ushort)s;
    }
    return;
  }

  __shared__ ushort As[128][64];
  __shared__ ushort Bs[128][64];
  const int wid = t >> 6, lane = t & 63;
  const int K = IN_DIM;

  const int nwg  = NWG_HS;
  const int orig = blockIdx.x;
  const int q = nwg >> 3, r = nwg & 7;
  const int xcd = orig & 7, idx = orig >> 3;
  const int swz = (xcd < r ? xcd * (q + 1) : r * (q + 1) + (xcd - r) * q) + idx;
  const int bxi = swz % GX_HS, byi0 = swz / GX_HS;

  const bool llm = (byi0 >= GY_USER);
  const int byi = llm ? byi0 - GY_USER : byi0;
  const ushort* A    = llm ? A_l : A_u;
  const ushort* Bt   = llm ? Bt_l : Bt_u;
  ushort* hs         = llm ? hs_l : hs_u;
  float* logit       = llm ? logL : logU;

  const int bm = byi * 128, bn = bxi * 128;
  const int lr = lane & 15, kg = lane >> 4;
  const int sw8 = lr & 7;
  const int mbase = (wid >> 1) * 64, nbase = (wid & 1) * 64;
  const int grow = lane >> 3;
  const int gcol = (((lane & 7) ^ grow)) * 8;

  f32x4 acc[4][4] = {};

  for (int k0 = 0; k0 < K; k0 += 64) {
#pragma unroll
    for (int c = 0; c < 4; ++c) {
      int ch = wid * 4 + c;
      GLOAD_LDS16(A  + (size_t)(bm + ch * 8 + grow) * K + k0 + gcol, &As[ch * 8][0]);
      GLOAD_LDS16(Bt + (size_t)(bn + ch * 8 + grow) * K + k0 + gcol, &Bs[ch * 8][0]);
    }
    asm volatile("s_waitcnt vmcnt(0)" ::: "memory");
    __syncthreads();
#pragma unroll
    for (int kb = 0; kb < 2; ++kb) {
      const int csw = ((kb * 4 + kg) ^ sw8) * 8;
      bf16x8 av[4], bv[4];
#pragma unroll
      for (int m = 0; m < 4; ++m)
        av[m] = *(const bf16x8*)&As[mbase + m * 16 + lr][csw];
#pragma unroll
      for (int n = 0; n < 4; ++n)
        bv[n] = *(const bf16x8*)&Bs[nbase + n * 16 + lr][csw];
#pragma unroll
      for (int m = 0; m < 4; ++m)
#pragma unroll
        for (int n = 0; n < 4; ++n)
          acc[m][n] = __builtin_amdgcn_mfma_f32_16x16x32_bf16(av[m], bv[n], acc[m][n], 0, 0, 0);
    }
    __syncthreads();
  }

  if (bxi == GX_HS - 1) {
    if (nbase == 0) {
#pragma unroll
      for (int m = 0; m < 4; ++m)
#pragma unroll
        for (int j = 0; j < 4; ++j) {
          int row = bm + mbase + m * 16 + kg * 4 + j;
          logit[(size_t)row * 16 + lr] = acc[m][0][j];
        }
    }
    return;
  }

#pragma unroll
  for (int m = 0; m < 4; ++m)
#pragma unroll
    for (int j = 0; j < 4; ++j) {
      int row = bm + mbase + m * 16 + kg * 4 + j;
#pragma unroll
      for (int n = 0; n < 4; ++n) {
        int col = bn + nbase + n * 16 + lr;
        hs[(size_t)row * SEM + col] = f2b(acc[m][n][j]);
      }
    }
}

// ------- fused beta + out GEMM: per block = 64 nodes (128 Z rows) ----------
// Phase 1: T-GEMM(Z,WtS) + tanh/W2 reduce + 2-way softmax -> betaL[64] (LDS).
// Phase 2: out[64x256] = (betaL combine of Z rows) @ WtO + out_b.
// Z is read from HBM once (phase 1); phase 2 re-read is L2-hot.
__global__ __launch_bounds__(256) void gemm_bo(
    const ushort* __restrict__ Z, const ushort* __restrict__ WtS,
    const float* __restrict__ b1, const float* __restrict__ W2,
    const ushort* __restrict__ WtO, float* __restrict__ out,
    const float* __restrict__ out_b)
{
  __shared__ ushort As[128][64];   // 16 KB (phase2 uses rows 0..63)
  __shared__ ushort Bs[256][64];   // 32 KB (phase1 uses rows 0..127)
  __shared__ float wsum[128][2];
  __shared__ float2 betaL[64];
  const int t = threadIdx.x;
  const int wid = t >> 6, lane = t & 63;
  const int K = SEM;

  const int nwg  = gridDim.x;
  const int orig = blockIdx.x;
  const int q = nwg >> 3, r = nwg & 7;
  const int xcd = orig & 7, idx = orig >> 3;
  const int swz = (xcd < r ? xcd * (q + 1) : r * (q + 1) + (xcd - r) * q) + idx;

  const int lr = lane & 15, kg = lane >> 4;
  const int sw8 = lr & 7;
  const int grow = lane >> 3;
  const int gcol = (((lane & 7) ^ grow)) * 8;

  // ---------------- phase 1: beta for the 64 nodes ----------------
  {
    const int bm = swz * 128;                 // interleaved Z row base
    const int mbase = (wid >> 1) * 64, nbase = (wid & 1) * 64;
    f32x4 acc[4][4] = {};
    for (int k0 = 0; k0 < K; k0 += 64) {
#pragma unroll
      for (int c = 0; c < 4; ++c) {
        int ch = wid * 4 + c;
        GLOAD_LDS16(Z   + (size_t)(bm + ch * 8 + grow) * K + k0 + gcol, &As[ch * 8][0]);
        GLOAD_LDS16(WtS + (size_t)(ch * 8 + grow) * K + k0 + gcol, &Bs[ch * 8][0]);
      }
      asm volatile("s_waitcnt vmcnt(0)" ::: "memory");
      __syncthreads();
#pragma unroll
      for (int kb = 0; kb < 2; ++kb) {
        const int csw = ((kb * 4 + kg) ^ sw8) * 8;
        bf16x8 av[4], bv[4];
#pragma unroll
        for (int m = 0; m < 4; ++m)
          av[m] = *(const bf16x8*)&As[mbase + m * 16 + lr][csw];
#pragma unroll
        for (int n = 0; n < 4; ++n)
          bv[n] = *(const bf16x8*)&Bs[nbase + n * 16 + lr][csw];
#pragma unroll
        for (int m = 0; m < 4; ++m)
#pragma unroll
          for (int n = 0; n < 4; ++n)
            acc[m][n] = __builtin_amdgcn_mfma_f32_16x16x32_bf16(av[m], bv[n], acc[m][n], 0, 0, 0);
      }
      __syncthreads();
    }

    float part[4][4];
#pragma unroll
    for (int m = 0; m < 4; ++m)
#pragma unroll
      for (int j = 0; j < 4; ++j) {
        float s = 0.f;
#pragma unroll
        for (int n = 0; n < 4; ++n) {
          int col = nbase + n * 16 + lr;
          float tv = acc[m][n][j] + b1[col];
          tv = fminf(fmaxf(tv, -20.f), 20.f);      // NaN/Inf-safe clamp
          float e = fexp2(2.f * LOG2E * tv);
          s += ((e - 1.f) / (e + 1.f)) * W2[col];
        }
        part[m][j] = s;
      }
#pragma unroll
    for (int off = 1; off < 16; off <<= 1)
#pragma unroll
      for (int m = 0; m < 4; ++m)
#pragma unroll
        for (int j = 0; j < 4; ++j)
          part[m][j] += __shfl_xor(part[m][j], off);
    if (lr == 0) {
#pragma unroll
      for (int m = 0; m < 4; ++m)
#pragma unroll
        for (int j = 0; j < 4; ++j)
          wsum[mbase + m * 16 + kg * 4 + j][wid & 1] = part[m][j];
    }
    __syncthreads();
    if (t < 64) {
      float w0 = wsum[2 * t][0] + wsum[2 * t][1];
      float w1 = wsum[2 * t + 1][0] + wsum[2 * t + 1][1];
      float mx = fmaxf(w0, w1);
      float e0 = fexp2((w0 - mx) * LOG2E), e1 = fexp2((w1 - mx) * LOG2E);
      float s = e0 + e1;
      betaL[t] = make_float2(e0 / s, e1 / s);
    }
    __syncthreads();
  }

  // ---------------- phase 2: out[64 x 256] ----------------
  {
    const int bm2 = swz * 64;                 // node base
    const int mbase = (wid >> 1) * 32, nbase = (wid & 1) * 128;
    f32x4 acc[2][8] = {};
    for (int k0 = 0; k0 < K; k0 += 64) {
#pragma unroll
      for (int c = 0; c < 8; ++c) {
        int ch = wid * 8 + c;                 // 0..31
        GLOAD_LDS16(WtO + (size_t)(ch * 8 + grow) * K + k0 + gcol, &Bs[ch * 8][0]);
      }
#pragma unroll
      for (int c = 0; c < 2; ++c) {
        int ch = wid * 2 + c;                 // 0..7
        int rl = ch * 8 + grow;               // 0..63 ; rl&7 == grow
        int node = bm2 + rl;
        const ushort* z0p = Z + (size_t)(2 * node) * SEM + k0 + (lane & 7) * 8;
        const ushort* z1p = z0p + SEM;
        float2 bb = betaL[rl];
        uint4 a0 = *(const uint4*)z0p;
        uint4 a1 = *(const uint4*)z1p;
        uint rpk[4];
#pragma unroll
        for (int qq = 0; qq < 4; ++qq) {
          uint x0 = ((const uint*)&a0)[qq], x1 = ((const uint*)&a1)[qq];
          float lo = bb.x * b2f(x0 & 0xffffu) + bb.y * b2f(x1 & 0xffffu);
          float hi = bb.x * b2f(x0 >> 16)     + bb.y * b2f(x1 >> 16);
          rpk[qq] = (uint)f2b(lo) | ((uint)f2b(hi) << 16);
        }
        *(uint4*)&As[rl][gcol] = make_uint4(rpk[0], rpk[1], rpk[2], rpk[3]);
      }
      asm volatile("s_waitcnt vmcnt(0)" ::: "memory");
      __syncthreads();
#pragma unroll
      for (int kb = 0; kb < 2; ++kb) {
        const int csw = ((kb * 4 + kg) ^ sw8) * 8;
        bf16x8 av[2], bv[8];
#pragma unroll
        for (int m = 0; m < 2; ++m)
          av[m] = *(const bf16x8*)&As[mbase + m * 16 + lr][csw];
#pragma unroll
        for (int n = 0; n < 8; ++n)
          bv[n] = *(const bf16x8*)&Bs[nbase + n * 16 + lr][csw];
#pragma unroll
        for (int m = 0; m < 2; ++m)
#pragma unroll
          for (int n = 0; n < 8; ++n)
            acc[m][n] = __builtin_amdgcn_mfma_f32_16x16x32_bf16(av[m], bv[n], acc[m][n], 0, 0, 0);
      }
      __syncthreads();
    }

#pragma unroll
    for (int m = 0; m < 2; ++m)
#pragma unroll
      for (int j = 0; j < 4; ++j) {
        int node = bm2 + mbase + m * 16 + kg * 4 + j;
        if (node >= N_USER) continue;
#pragma unroll
        for (int n = 0; n < 8; ++n) {
          int col = nbase + n * 16 + lr;
          out[(size_t)node * OUT_DIM + col] = acc[m][n][j] + out_b[col];
        }
      }
  }
}

// ---------------- mega prep kernel (grid-strided) --------------------------
constexpr int NB_FOLD  = cdiv(IN_DIM * 16, 256);            // 48
constexpr int NB_CASTU = N_USER * IN_DIM / 8 / 256;         // 18750
constexpr int NB_CASTL = N_LLM * IN_DIM / 8 / 256;          // 1875
constexpr int NB_TTW   = (IN_DIM / 64) * (SEM / 64);        // 96 (x2)
constexpr int NB_TTS   = (SEM / 64) * (HID / 64);           // 16
constexpr int NB_TTO   = (SEM / 64) * (OUT_DIM / 64);       // 32
constexpr int NB_E1    = cdiv(2 * NE, 256);                 // 3125
constexpr int PB0 = NB_FOLD;
constexpr int PB1 = PB0 + NB_CASTU;
constexpr int PB2 = PB1 + NB_CASTL;
constexpr int PB3 = PB2 + NB_TTW;
constexpr int PB4 = PB3 + NB_TTW;
constexpr int PB5 = PB4 + NB_TTS;
constexpr int PB6 = PB5 + NB_TTO;
constexpr int PB7 = PB6 + NB_E1;
constexpr int PREP_GRID = 2048;

__device__ __forceinline__ void tt_body(const float* __restrict__ W,
                                        ushort* __restrict__ Bt,
                                        int K, int Nw, int tile,
                                        float (*lds)[65], int t)
{
  const int tiles_n = Nw >> 6;
  const int tk = tile / tiles_n, tn = tile - tk * tiles_n;
  const int k0 = tk << 6, n0 = tn << 6;
#pragma unroll
  for (int i = 0; i < 16; ++i) {
    int idx = t + i * 256;
    int rr = idx >> 6, cc = idx & 63;
    lds[rr][cc] = W[(size_t)(k0 + rr) * Nw + n0 + cc];
  }
  __syncthreads();
#pragma unroll
  for (int i = 0; i < 4; ++i) {
    int idx = t + i * 256;                 // 0..1023
    int cc = idx >> 4;                     // 0..63 (output row = n0+cc)
    int rq = (idx & 15) * 4;               // 0,4,...,60
    uint lo = (uint)f2b(lds[rq][cc])     | ((uint)f2b(lds[rq + 1][cc]) << 16);
    uint hi = (uint)f2b(lds[rq + 2][cc]) | ((uint)f2b(lds[rq + 3][cc]) << 16);
    *(uint2*)(Bt + (size_t)(n0 + cc) * K + k0 + rq) = make_uint2(lo, hi);
  }
  __syncthreads();
}

__device__ __forceinline__ void cast_body(const float* __restrict__ x,
                                          ushort* __restrict__ xb, int i)
{
  const float4 a = *(const float4*)(x + (size_t)i * 8);
  const float4 c = *(const float4*)(x + (size_t)i * 8 + 4);
  uint4 o;
  o.x = (uint)f2b(a.x) | ((uint)f2b(a.y) << 16);
  o.y = (uint)f2b(a.z) | ((uint)f2b(a.w) << 16);
  o.z = (uint)f2b(c.x) | ((uint)f2b(c.y) << 16);
  o.w = (uint)f2b(c.z) | ((uint)f2b(c.w) << 16);
  *(uint4*)(xb + (size_t)i * 8) = o;
}

__global__ __launch_bounds__(256) void prep_kernel(
    const float* __restrict__ x_user, const float* __restrict__ x_llm,
    ushort* __restrict__ xb_u, ushort* __restrict__ xb_l,
    const float* __restrict__ Wdst0, const float* __restrict__ adst0,
    const float* __restrict__ Wdst1, const float* __restrict__ adst1,
    const float* __restrict__ Wsrc1, const float* __restrict__ asrc1,
    const float* __restrict__ Wsrc0, const float* __restrict__ asrc0,
    ushort* __restrict__ Wt1x, ushort* __restrict__ Wt0x,
    const float* __restrict__ sem_W1, ushort* __restrict__ WtS,
    const float* __restrict__ out_W, ushort* __restrict__ WtO,
    const int* __restrict__ dst0, const int* __restrict__ dst1,
    int* __restrict__ deg, int* __restrict__ rank)
{
  __shared__ float lds[64][65];   // 16.6 KB, used by transpose sections
  const int t = threadIdx.x;
  for (int b = blockIdx.x; b < PB7; b += PREP_GRID) {
    if (b < PB0) {
      int idxg = b * 256 + t;
      if (idxg < IN_DIM * 16) {
        int k = idxg >> 4, hh = idxg & 15;
        const float* W;
        const float* att;
        if (hh < 4)       { W = Wdst0; att = adst0; }
        else if (hh < 8)  { W = Wdst1; att = adst1; }
        else if (hh < 12) { W = Wsrc1; att = asrc1; }
        else              { W = Wsrc0; att = asrc0; }
        int h = hh & 3;
        float s = 0.f;
#pragma unroll 4
        for (int c = 0; c < HID; ++c)
          s += W[(size_t)k * SEM + h * HID + c] * att[h * HID + c];
        if (hh < 12) Wt1x[(size_t)(512 + hh) * IN_DIM + k] = f2b(s);
        else         Wt0x[(size_t)(512 + h) * IN_DIM + k] = f2b(s);
      }
    } else if (b < PB1) {
      cast_body(x_user, xb_u, (b - PB0) * 256 + t);
    } else if (b < PB2) {
      cast_body(x_llm, xb_l, (b - PB1) * 256 + t);
    } else if (b < PB3) {
      tt_body(Wsrc0, Wt0x, IN_DIM, SEM, b - PB2, lds, t);
    } else if (b < PB4) {
      tt_body(Wsrc1, Wt1x, IN_DIM, SEM, b - PB3, lds, t);
    } else if (b < PB5) {
      tt_body(sem_W1, WtS, SEM, HID, b - PB4, lds, t);
    } else if (b < PB6) {
      tt_body(out_W, WtO, SEM, OUT_DIM, b - PB5, lds, t);
    } else {
      int e = (b - PB6) * 256 + t;
      if (e < 2 * NE) {
        int d = (e < NE) ? dst0[e] : (dst1[e - NE] + N_USER);
        rank[e] = atomicAdd(&deg[d], 1);
      }
    }
  }
}

// -------- 3-phase scan over deg[0..n) --------------------------------------
__global__ __launch_bounds__(256) void scan1(const int* __restrict__ deg,
                                             int* __restrict__ bsum, int n)
{
  __shared__ int sm[256];
  int b = blockIdx.x, t = threadIdx.x;
  int base = b * 1024 + t * 4;
  int s = 0;
#pragma unroll
  for (int i = 0; i < 4; ++i) if (base + i < n) s += deg[base + i];
  sm[t] = s;
  __syncthreads();
  for (int off = 128; off > 0; off >>= 1) {
    if (t < off) sm[t] += sm[t + off];
    __syncthreads();
  }
  if (t == 0) bsum[b] = sm[0];
}

__global__ __launch_bounds__(128) void scan2(const int* __restrict__ bsum,
                                             int* __restrict__ boff, int nb,
                                             int* __restrict__ rp_tail, int tailval)
{
  __shared__ int sm[128];
  int t = threadIdx.x;
  int v = (t < nb) ? bsum[t] : 0;
  sm[t] = v;
  __syncthreads();
  for (int off = 1; off < 128; off <<= 1) {
    int x = (t >= off) ? sm[t - off] : 0;
    __syncthreads();
    sm[t] += x;
    __syncthreads();
  }
  if (t < nb) boff[t] = sm[t] - v;
  if (t == 0) *rp_tail = tailval;
}

__global__ __launch_bounds__(256) void scan3(const int* __restrict__ deg,
                                             const int* __restrict__ boff,
                                             int* __restrict__ rp, int n)
{
  __shared__ int sm[256];
  int b = blockIdx.x, t = threadIdx.x;
  int base = b * 1024 + t * 4;
  int v[4];
#pragma unroll
  for (int i = 0; i < 4; ++i) v[i] = (base + i < n) ? deg[base + i] : 0;
  int tsum = v[0] + v[1] + v[2] + v[3];
  sm[t] = tsum;
  __syncthreads();
  for (int off = 1; off < 256; off <<= 1) {
    int x = (t >= off) ? sm[t - off] : 0;
    __syncthreads();
    sm[t] += x;
    __syncthreads();
  }
  int run = sm[t] - tsum + boff[b];
#pragma unroll
  for (int i = 0; i < 4; ++i) {
    if (base + i < n) rp[base + i] = run;
    run += v[i];
  }
}

// -------- unified aggregation: ONE WAVE per dst node -----------------------
// Writes Z in interleaved layout: row = 2*nd + path.
__global__ __launch_bounds__(64) void agg_kernel(
    const ushort* __restrict__ hs0, const ushort* __restrict__ hs1,
    const ushort* __restrict__ srcs,
    const float* __restrict__ logitL, const float* __restrict__ logitU,
    const int* __restrict__ rp,
    const float* __restrict__ bias0, const float* __restrict__ bias1,
    ushort* __restrict__ Zout)
{
  __shared__ ushort s_src[64];
  __shared__ float  s_ev[64][4];
  int node = blockIdx.x, lane = threadIdx.x;
  bool p1 = (node >= N_USER);
  const ushort* hs   = p1 ? hs1 : hs0;
  const float*  bias = p1 ? bias1 : bias0;
  int nd = p1 ? node - N_USER : node;
  float4 ad4 = *(const float4*)(logitU + (size_t)nd * 16 + (p1 ? 4 : 0));
  ad4.x *= LOG2E; ad4.y *= LOG2E; ad4.z *= LOG2E; ad4.w *= LOG2E;
  const float* asbase = p1 ? (logitU + 8) : logitL;
  int h  = lane >> 4;
  int cb = lane * 8;
  float acc[8] = {};
  float dsum = 0.f;
  int jb = rp[node], je = rp[node + 1];
  for (int j0 = jb; j0 < je; j0 += 64) {
    int n = min(64, je - j0);
    __syncthreads();
    if (lane < n) {
      int s = srcs[j0 + lane];
      s_src[lane] = (ushort)s;
      float4 as4 = *(const float4*)(asbase + (size_t)s * 16);
      float v0 = as4.x * LOG2E + ad4.x, v1 = as4.y * LOG2E + ad4.y;
      float v2 = as4.z * LOG2E + ad4.z, v3 = as4.w * LOG2E + ad4.w;
      v0 = (v0 > 0.f) ? v0 : 0.2f * v0;
      v1 = (v1 > 0.f) ? v1 : 0.2f * v1;
      v2 = (v2 > 0.f) ? v2 : 0.2f * v2;
      v3 = (v3 > 0.f) ? v3 : 0.2f * v3;
      s_ev[lane][0] = fexp2(v0);
      s_ev[lane][1] = fexp2(v1);
      s_ev[lane][2] = fexp2(v2);
      s_ev[lane][3] = fexp2(v3);
    }
    __syncthreads();
#pragma unroll 4
    for (int j = 0; j < n; ++j) {
      int s = __builtin_amdgcn_readfirstlane((int)s_src[j]);
      float e = s_ev[j][h];
      const uint4 pv = *(const uint4*)(hs + ((size_t)s << 9) + cb);
      acc[0] += b2f(pv.x & 0xffffu) * e;  acc[1] += b2f(pv.x >> 16) * e;
      acc[2] += b2f(pv.y & 0xffffu) * e;  acc[3] += b2f(pv.y >> 16) * e;
      acc[4] += b2f(pv.z & 0xffffu) * e;  acc[5] += b2f(pv.z >> 16) * e;
      acc[6] += b2f(pv.w & 0xffffu) * e;  acc[7] += b2f(pv.w >> 16) * e;
      dsum += e;
    }
  }
  float inv = 1.f / (dsum + 1e-16f);
  float4 b4a = *(const float4*)(bias + cb);
  float4 b4b = *(const float4*)(bias + cb + 4);
  float bb[8] = { b4a.x, b4a.y, b4a.z, b4a.w, b4b.x, b4b.y, b4b.z, b4b.w };
  uint4 o;
  uint* op = (uint*)&o;
#pragma unroll
  for (int i = 0; i < 4; ++i) {
    float z0 = acc[2 * i]     * inv + bb[2 * i];
    float z1 = acc[2 * i + 1] * inv + bb[2 * i + 1];
    z0 = (z0 > 0.f) ? z0 : fexp2(z0 * LOG2E) - 1.f;
    z1 = (z1 > 0.f) ? z1 : fexp2(z1 * LOG2E) - 1.f;
    op[i] = (uint)f2b(z0) | ((uint)f2b(z1) << 16);
  }
  int zrow = 2 * nd + (p1 ? 1 : 0);
  *(uint4*)(Zout + (size_t)zrow * SEM + cb) = o;
}

extern "C" void kernel_launch(void* const* d_in, const int* in_sizes, int n_in,
                              void* d_out, int out_size, void* d_ws, size_t ws_size,
                              hipStream_t stream)
{
  const float* x_user = (const float*)d_in[0];
  const float* x_llm  = (const float*)d_in[1];
  const int* src0 = (const int*)d_in[2];
  const int* dst0 = (const int*)d_in[3];
  const int* src1 = (const int*)d_in[4];
  const int* dst1 = (const int*)d_in[5];
  const float* Wsrc0 = (const float*)d_in[6];
  const float* Wdst0 = (const float*)d_in[7];
  const float* asrc0 = (const float*)d_in[8];
  const float* adst0 = (const float*)d_in[9];
  const float* bias0 = (const float*)d_in[10];
  const float* Wsrc1 = (const float*)d_in[11];
  const float* Wdst1 = (const float*)d_in[12];
  const float* asrc1 = (const float*)d_in[13];
  const float* adst1 = (const float*)d_in[14];
  const float* bias1 = (const float*)d_in[15];
  const float* sem_W1 = (const float*)d_in[16];
  const float* sem_b1 = (const float*)d_in[17];
  const float* sem_W2 = (const float*)d_in[18];
  const float* out_W  = (const float*)d_in[19];
  const float* out_b  = (const float*)d_in[20];

  char* ws = (char*)d_ws;
  size_t off = 0;
  auto alloc = [&](size_t bytes) -> size_t {
    size_t o = off;
    off += (bytes + 255) & ~(size_t)255;
    return o;
  };

  size_t xbu_off  = alloc((size_t)MP_USER * IN_DIM * 2);
  size_t xbl_off  = alloc((size_t)MP_LLM  * IN_DIM * 2);
  size_t wt0_off  = alloc((size_t)640 * IN_DIM * 2);
  size_t wt1_off  = alloc((size_t)640 * IN_DIM * 2);
  size_t wts_off  = alloc((size_t)HID * SEM * 2);
  size_t wto_off  = alloc((size_t)OUT_DIM * SEM * 2);
  size_t hs0_off  = alloc((size_t)MP_LLM  * SEM * 2);
  size_t hs1_off  = alloc((size_t)MP_USER * SEM * 2);
  size_t Z_off    = alloc((size_t)MP_2U   * SEM * 2);
  size_t sc_off   = alloc((size_t)2 * NE * 2);
  size_t rank_off = alloc((size_t)2 * NE * 4);
  size_t lgu_off  = alloc((size_t)MP_USER * 16 * 4);
  size_t lgl_off  = alloc((size_t)MP_LLM  * 16 * 4);
  size_t deg_off  = alloc((size_t)2 * N_USER * 4);         // zeroed
  size_t zero_end = off;
  size_t rp_off   = alloc((size_t)(2 * N_USER + 1) * 4);
  size_t bs_off   = alloc((size_t)128 * 4);
  size_t bo_off   = alloc((size_t)128 * 4);

  ushort* xb_u  = (ushort*)(ws + xbu_off);
  ushort* xb_l  = (ushort*)(ws + xbl_off);
  ushort* Wt0x  = (ushort*)(ws + wt0_off);
  ushort* Wt1x  = (ushort*)(ws + wt1_off);
  ushort* WtS   = (ushort*)(ws + wts_off);
  ushort* WtO   = (ushort*)(ws + wto_off);
  ushort* hs0b  = (ushort*)(ws + hs0_off);
  ushort* hs1b  = (ushort*)(ws + hs1_off);
  ushort* Zsw   = (ushort*)(ws + Z_off);
  ushort* scsr  = (ushort*)(ws + sc_off);
  int*    rank  = (int*)(ws + rank_off);
  float*  logU  = (float*)(ws + lgu_off);
  float*  logL  = (float*)(ws + lgl_off);
  int*    deg   = (int*)(ws + deg_off);
  int*    rp    = (int*)(ws + rp_off);
  int*    bsum  = (int*)(ws + bs_off);
  int*    boff  = (int*)(ws + bo_off);

  hipMemsetAsync(ws + deg_off, 0, zero_end - deg_off, stream);
  hipMemsetAsync(Wt0x + (size_t)512 * IN_DIM, 0, (size_t)128 * IN_DIM * 2, stream);
  hipMemsetAsync(Wt1x + (size_t)512 * IN_DIM, 0, (size_t)128 * IN_DIM * 2, stream);

  // mega prep (grid-strided): fold + casts + tiled transposes + degree/rank
  prep_kernel<<<PREP_GRID, 256, 0, stream>>>(
      x_user, x_llm, xb_u, xb_l,
      Wdst0, adst0, Wdst1, adst1, Wsrc1, asrc1, Wsrc0, asrc0,
      Wt1x, Wt0x, sem_W1, WtS, out_W, WtO,
      dst0, dst1, deg, rank);

  // CSR row pointers
  const int NTOT = 2 * N_USER;
  const int NB = cdiv(NTOT, 1024);   // 98
  scan1<<<NB, 256, 0, stream>>>(deg, bsum, NTOT);
  scan2<<<1, 128, 0, stream>>>(bsum, boff, NB, rp + NTOT, 2 * NE);
  scan3<<<NB, 256, 0, stream>>>(deg, boff, rp, NTOT);

  // merged hs GEMMs + CSR scatter (independent work in one dispatch)
  gemm_hs_sc<<<NWG_HS + NB_SC, 256, 0, stream>>>(
      xb_u, xb_l, Wt1x, Wt0x, hs1b, hs0b, logU, logL,
      src0, dst0, src1, dst1, rp, rank, scsr);

  // unified aggregation (one wave per node) -> bf16 Z (interleaved rows)
  agg_kernel<<<NTOT, 64, 0, stream>>>(hs0b, hs1b, scsr, logL, logU, rp,
                                      bias0, bias1, Zsw);

  // fused beta + out GEMM (Z read once; beta never leaves LDS)
  gemm_bo<<<MP_2U / 128, 256, 0, stream>>>(Zsw, WtS, sem_b1, sem_W2,
                                           WtO, (float*)d_out, out_b);
}